// Round 1
// baseline (6139.219 us; speedup 1.0000x reference)
//
#include <hip/hip_runtime.h>

#define NB 32
#define NT 15

// Workspace layout (uint8 fire-time maps, 15 == never fires):
//  ft0  : (B,18,36,36)  input, pad=2 baked in            746496 B
//  ft1  : (B,90,30,30)  layer-1 fire times              2592000 B
//  ft1p : (B,90,17,17)  pool2x2s2 + pad=1                832320 B
//  ft2  : (B,250,13,13) layer-2 fire times              1352000 B
//  ft2p : (B,250,8,8)   pool3x3s3 + pad=2                512000 B
// total ~6.03 MB

// ---------- K0: input fire times (padded plane) ----------
__global__ __launch_bounds__(256) void k_ft0(const float* __restrict__ inp,
                                             unsigned char* __restrict__ ft0) {
    int idx = blockIdx.x * 256 + threadIdx.x;
    const int total = NB * 18 * 36 * 36;
    if (idx >= total) return;
    int xx = idx % 36, rest = idx / 36;
    int yy = rest % 36; rest /= 36;
    int c = rest % 18;  int b = rest / 18;
    int ft = 15;
    int x = xx - 2, y = yy - 2;
    if (x >= 0 && x < 32 && y >= 0 && y < 32) {
        int cnt = 0;
        const float* p = inp + ((size_t)(b * NT) * 18 + c) * 1024 + y * 32 + x;
#pragma unroll
        for (int t = 0; t < NT; t++) cnt += (p[(size_t)t * 18 * 1024] != 0.f);
        ft = 15 - cnt;   // cumulative wave: count of ones == 15 - fire_time
    }
    ft0[idx] = (unsigned char)ft;
}

// ---------- K1: conv1 (18->90, 7x7) + fire(thr=15) ----------
__global__ __launch_bounds__(256) void k_conv1(const unsigned char* __restrict__ ft0,
                                               const float* __restrict__ w1,
                                               unsigned char* __restrict__ ft1) {
    int px = blockIdx.x * 256 + threadIdx.x;   // 0..899
    if (px >= 900) return;
    int f = blockIdx.y, b = blockIdx.z;
    int oy = px / 30, ox = px - oy * 30;
    float acc[NT];
#pragma unroll
    for (int t = 0; t < NT; t++) acc[t] = 0.f;
    const unsigned char* fb = ft0 + (size_t)b * 18 * 1296;
    const float* wf = w1 + (size_t)f * 882;    // f uniform per block -> scalar loads
    for (int c = 0; c < 18; c++) {
#pragma unroll
        for (int ky = 0; ky < 7; ky++) {
            const unsigned char* row = fb + c * 1296 + (oy + ky) * 36 + ox;
            const float* wr = wf + c * 49 + ky * 7;
#pragma unroll
            for (int kx = 0; kx < 7; kx++) {
                int fv = row[kx];
                float w = wr[kx];
#pragma unroll
                for (int t = 0; t < NT; t++) acc[t] += (fv <= t) ? w : 0.f;
            }
        }
    }
    int ft = 15;
#pragma unroll
    for (int t = NT - 1; t >= 0; t--) if (acc[t] > 15.0f) ft = t;
    ft1[((size_t)b * 90 + f) * 900 + px] = (unsigned char)ft;
}

// ---------- K2: pool 2x2 s2 (min fire time) + pad=1 ----------
__global__ __launch_bounds__(256) void k_pool1(const unsigned char* __restrict__ ft1,
                                               unsigned char* __restrict__ ft1p) {
    int idx = blockIdx.x * 256 + threadIdx.x;
    const int total = NB * 90 * 17 * 17;
    if (idx >= total) return;
    int xx = idx % 17, rest = idx / 17;
    int yy = rest % 17; rest /= 17;
    int c = rest % 90;  int b = rest / 90;
    int ft = 15;
    if (xx >= 1 && xx < 16 && yy >= 1 && yy < 16) {
        const unsigned char* p = ft1 + ((size_t)b * 90 + c) * 900 + (yy - 1) * 2 * 30 + (xx - 1) * 2;
        int m = p[0];
        m = min(m, (int)p[1]);
        m = min(m, (int)p[30]);
        m = min(m, (int)p[31]);
        ft = m;
    }
    ft1p[idx] = (unsigned char)ft;
}

// ---------- K3: conv2 (90->250, 5x5) + fire(thr=10) ----------
__global__ __launch_bounds__(192) void k_conv2(const unsigned char* __restrict__ ft1p,
                                               const float* __restrict__ w2,
                                               unsigned char* __restrict__ ft2) {
    int tid = threadIdx.x;
    if (tid >= 169) return;
    int f = blockIdx.y, b = blockIdx.z;
    int oy = tid / 13, ox = tid - oy * 13;
    float acc[NT];
#pragma unroll
    for (int t = 0; t < NT; t++) acc[t] = 0.f;
    const unsigned char* fb = ft1p + (size_t)b * 90 * 289;
    const float* wf = w2 + (size_t)f * 2250;
    for (int c = 0; c < 90; c++) {
#pragma unroll
        for (int ky = 0; ky < 5; ky++) {
            const unsigned char* row = fb + c * 289 + (oy + ky) * 17 + ox;
            const float* wr = wf + c * 25 + ky * 5;
#pragma unroll
            for (int kx = 0; kx < 5; kx++) {
                int fv = row[kx];
                float w = wr[kx];
#pragma unroll
                for (int t = 0; t < NT; t++) acc[t] += (fv <= t) ? w : 0.f;
            }
        }
    }
    int ft = 15;
#pragma unroll
    for (int t = NT - 1; t >= 0; t--) if (acc[t] > 10.0f) ft = t;
    ft2[((size_t)b * 250 + f) * 169 + tid] = (unsigned char)ft;
}

// ---------- K4: pool 3x3 s3 (min fire time) + pad=2 ----------
__global__ __launch_bounds__(256) void k_pool2(const unsigned char* __restrict__ ft2,
                                               unsigned char* __restrict__ ft2p) {
    int idx = blockIdx.x * 256 + threadIdx.x;
    const int total = NB * 250 * 8 * 8;
    if (idx >= total) return;
    int xx = idx % 8, rest = idx / 8;
    int yy = rest % 8; rest /= 8;
    int c = rest % 250; int b = rest / 250;
    int ft = 15;
    if (xx >= 2 && xx < 6 && yy >= 2 && yy < 6) {
        const unsigned char* p = ft2 + ((size_t)b * 250 + c) * 169 + (yy - 2) * 3 * 13 + (xx - 2) * 3;
        int m = 15;
#pragma unroll
        for (int dy = 0; dy < 3; dy++)
#pragma unroll
            for (int dx = 0; dx < 3; dx++) m = min(m, (int)p[dy * 13 + dx]);
        ft = m;
    }
    ft2p[idx] = (unsigned char)ft;
}

// ---------- K5: conv3 (250->200, 5x5) -> pot3 dense (B,T,200,4,4) ----------
__global__ __launch_bounds__(256) void k_conv3(const unsigned char* __restrict__ ft2p,
                                               const float* __restrict__ w3,
                                               float* __restrict__ out) {
    int tid = threadIdx.x;
    int fl = tid >> 4, px = tid & 15;
    int f = blockIdx.x * 16 + fl, b = blockIdx.z;
    if (f >= 200) return;
    int oy = px >> 2, ox = px & 3;
    float acc[NT];
#pragma unroll
    for (int t = 0; t < NT; t++) acc[t] = 0.f;
    const unsigned char* fb = ft2p + (size_t)b * 250 * 64;
    const float* wf = w3 + (size_t)f * 6250;
    for (int c = 0; c < 250; c++) {
#pragma unroll
        for (int ky = 0; ky < 5; ky++) {
            const unsigned char* row = fb + c * 64 + (oy + ky) * 8 + ox;
            const float* wr = wf + c * 25 + ky * 5;
#pragma unroll
            for (int kx = 0; kx < 5; kx++) {
                int fv = row[kx];
                float w = wr[kx];
#pragma unroll
                for (int t = 0; t < NT; t++) acc[t] += (fv <= t) ? w : 0.f;
            }
        }
    }
    // out layout: [0:32) = cls (float), [32:) = pot3 (B,T,200,4,4) C-order
    float* o = out + 32 + (size_t)b * NT * 3200 + f * 16 + px;
#pragma unroll
    for (int t = 0; t < NT; t++) o[(size_t)t * 3200] = acc[t];
}

// ---------- K6: winner-take-all classification ----------
__global__ __launch_bounds__(256) void k_winner(const float* __restrict__ outp,
                                                float* __restrict__ outc) {
    int b = blockIdx.x, tid = threadIdx.x;
    const float* p14 = outp + 32 + ((size_t)b * NT + 14) * 3200;  // pot3 at t=14
    __shared__ float sv[256];
    __shared__ int   si[256];
    // phase 1: max of relu(pot14)
    float m = 0.f;
    for (int j = tid; j < 3200; j += 256) {
        float v = p14[j];
        if (v > 0.f && v > m) m = v;
    }
    sv[tid] = m;
    __syncthreads();
    for (int s = 128; s > 0; s >>= 1) {
        if (tid < s) sv[tid] = fmaxf(sv[tid], sv[tid + s]);
        __syncthreads();
    }
    float vofs = 15.f * sv[0];
    __syncthreads();
    // phase 2: argmax of total = fire ? pot14 + vofs : 0, first-index tie-break
    float bestv = 0.f; int besti = 0x3fffffff;
    for (int j = tid; j < 3200; j += 256) {
        float v = p14[j];
        float tot = (v > 0.f) ? v + vofs : 0.f;
        if (tot > bestv) { bestv = tot; besti = j; }   // ascending j keeps first
    }
    sv[tid] = bestv; si[tid] = besti;
    __syncthreads();
    for (int s = 128; s > 0; s >>= 1) {
        if (tid < s) {
            if (sv[tid + s] > sv[tid] || (sv[tid + s] == sv[tid] && si[tid + s] < si[tid])) {
                sv[tid] = sv[tid + s]; si[tid] = si[tid + s];
            }
        }
        __syncthreads();
    }
    if (tid == 0) {
        float mx = sv[0];
        int cls = (mx != 0.f) ? ((si[0] / 16) / 20) : -1;
        outc[b] = (float)cls;
    }
}

extern "C" void kernel_launch(void* const* d_in, const int* in_sizes, int n_in,
                              void* d_out, int out_size, void* d_ws, size_t ws_size,
                              hipStream_t stream) {
    const float* inp = (const float*)d_in[0];
    const float* w1  = (const float*)d_in[1];
    const float* w2  = (const float*)d_in[2];
    const float* w3  = (const float*)d_in[3];
    float* out = (float*)d_out;

    unsigned char* ws   = (unsigned char*)d_ws;
    unsigned char* ft0  = ws;
    unsigned char* ft1  = ft0 + 746496;
    unsigned char* ft1p = ft1 + 2592000;
    unsigned char* ft2  = ft1p + 832320;
    unsigned char* ft2p = ft2 + 1352000;

    hipLaunchKernelGGL(k_ft0,   dim3((NB * 18 * 36 * 36 + 255) / 256), dim3(256), 0, stream, inp, ft0);
    hipLaunchKernelGGL(k_conv1, dim3(4, 90, NB),  dim3(256), 0, stream, ft0, w1, ft1);
    hipLaunchKernelGGL(k_pool1, dim3((NB * 90 * 289 + 255) / 256), dim3(256), 0, stream, ft1, ft1p);
    hipLaunchKernelGGL(k_conv2, dim3(1, 250, NB), dim3(192), 0, stream, ft1p, w2, ft2);
    hipLaunchKernelGGL(k_pool2, dim3((NB * 250 * 64 + 255) / 256), dim3(256), 0, stream, ft2, ft2p);
    hipLaunchKernelGGL(k_conv3, dim3(13, 1, NB),  dim3(256), 0, stream, ft2p, w3, out);
    hipLaunchKernelGGL(k_winner, dim3(NB), dim3(256), 0, stream, out, out);
}

// Round 2
// 1900.400 us; speedup vs baseline: 3.2305x; 3.2305x over previous
//
#include <hip/hip_runtime.h>

#define NB 32
#define NT 15

// Workspace layout:
//  ft0  : (B,18,36,36) u8 input fire times, pad=2 baked     746496 B
//  ft1  : (B,90,30,30) u8 layer-1 fire times               2592000 B
//  ft1p : (B,90,17,17) u8 pool2x2s2 + pad=1                 832320 B
//  ft2  : (B,250,13,13) u8 layer-2 fire times              1352000 B
//  ft2p : (B,250,8,8)  u8 pool3x3s3 + pad=2                 512000 B
//  wT1  : (883,90) f32 transposed w1 + zero row             317880 B
//  wT2  : (2251,250) f32 transposed w2 + zero row          2251000 B
// total ~8.6 MB

// ---------- K0: input fire times (padded plane) ----------
__global__ __launch_bounds__(256) void k_ft0(const float* __restrict__ inp,
                                             unsigned char* __restrict__ ft0) {
    int idx = blockIdx.x * 256 + threadIdx.x;
    const int total = NB * 18 * 36 * 36;
    if (idx >= total) return;
    int xx = idx % 36, rest = idx / 36;
    int yy = rest % 36; rest /= 36;
    int c = rest % 18;  int b = rest / 18;
    int ft = 15;
    int x = xx - 2, y = yy - 2;
    if (x >= 0 && x < 32 && y >= 0 && y < 32) {
        int cnt = 0;
        const float* p = inp + ((size_t)(b * NT) * 18 + c) * 1024 + y * 32 + x;
#pragma unroll
        for (int t = 0; t < NT; t++) cnt += (p[(size_t)t * 18 * 1024] != 0.f);
        ft = 15 - cnt;   // cumulative wave: #ones == 15 - fire_time
    }
    ft0[idx] = (unsigned char)ft;
}

// ---------- weight transpose (OIHW -> [tap][f]) with zero pad row ----------
template<int F, int K>
__global__ __launch_bounds__(256) void k_tr(const float* __restrict__ src,
                                            float* __restrict__ dst) {
    int idx = blockIdx.x * 256 + threadIdx.x;
    const int total = (K + 1) * F;      // extra zero row at k==K (pad target)
    if (idx >= total) return;
    int k = idx / F, f = idx - k * F;
    dst[idx] = (k < K) ? src[f * K + k] : 0.f;
}

// ---------- sorted-prefix conv: block = (b,px), lane = feature ----------
// ftin fire times -> counting sort by fire time in LDS -> each lane walks
// taps in fire-time order, 1 fp32 add per tap, threshold at bucket ends.
template<int TAPS, int F, int BLOCK, int KW, int OW, int NPX, int IH, int IPLANE, int CIN>
__global__ __launch_bounds__(BLOCK) void k_conv_sorted(const unsigned char* __restrict__ ftin,
                                                       const float* __restrict__ wT,
                                                       unsigned char* __restrict__ ftout,
                                                       float thr) {
    constexpr int PADCAP = TAPS + 15 * 8;     // bucket pad slack
    __shared__ unsigned char ftl[TAPS];
    __shared__ int perm[PADCAP];              // byte offsets into wT rows
    __shared__ int start[16];                 // padded bucket starts, start[15]=end
    __shared__ int cur[16];
    int tid = threadIdx.x;
    int px = blockIdx.x, b = blockIdx.y;
    int oy = px / OW, ox = px - oy * OW;
    const unsigned char* base = ftin + (size_t)b * CIN * IPLANE + oy * IH + ox;

    // stage RF fire times
    for (int i = tid; i < TAPS; i += BLOCK) {
        int c = i / (KW * KW); int rem = i - c * (KW * KW);
        int r = rem / KW; int x = rem - r * KW;
        ftl[i] = base[c * IPLANE + r * IH + x];
    }
    if (tid < 16) cur[tid] = 0;
    __syncthreads();
    // histogram (skip never-fire = 15)
    for (int i = tid; i < TAPS; i += BLOCK) {
        int v = ftl[i];
        if (v < 15) atomicAdd(&cur[v], 1);
    }
    __syncthreads();
    if (tid == 0) {
        int s = 0;
#pragma unroll
        for (int j = 0; j < 15; j++) { int c = cur[j]; start[j] = s; s += (c + 7) & ~7; }
        start[15] = s;
    }
    __syncthreads();
    int nnzp = start[15];
    if (tid < 15) cur[tid] = start[tid];
    const int zoff = TAPS * F * 4;            // zero weight row
    for (int i = tid; i < nnzp; i += BLOCK) perm[i] = zoff;
    __syncthreads();
    // scatter (order within bucket irrelevant)
    for (int i = tid; i < TAPS; i += BLOCK) {
        int v = ftl[i];
        if (v < 15) { int p = atomicAdd(&cur[v], 1); perm[p] = i * (F * 4); }
    }
    __syncthreads();

    // main: one add per tap, 8-wide software pipeline
    int f = tid < F ? tid : F - 1;
    const char* wb = (const char*)(wT + f);
    float acc = 0.f; int ft = 15;
    for (int s = 0; s < 15; s++) {
        int e = start[s + 1];
        for (int i = start[s]; i < e; i += 8) {
            int o0 = __builtin_amdgcn_readfirstlane(perm[i + 0]);
            int o1 = __builtin_amdgcn_readfirstlane(perm[i + 1]);
            int o2 = __builtin_amdgcn_readfirstlane(perm[i + 2]);
            int o3 = __builtin_amdgcn_readfirstlane(perm[i + 3]);
            int o4 = __builtin_amdgcn_readfirstlane(perm[i + 4]);
            int o5 = __builtin_amdgcn_readfirstlane(perm[i + 5]);
            int o6 = __builtin_amdgcn_readfirstlane(perm[i + 6]);
            int o7 = __builtin_amdgcn_readfirstlane(perm[i + 7]);
            float a0 = *(const float*)(wb + o0);
            float a1 = *(const float*)(wb + o1);
            float a2 = *(const float*)(wb + o2);
            float a3 = *(const float*)(wb + o3);
            float a4 = *(const float*)(wb + o4);
            float a5 = *(const float*)(wb + o5);
            float a6 = *(const float*)(wb + o6);
            float a7 = *(const float*)(wb + o7);
            acc += ((a0 + a1) + (a2 + a3)) + ((a4 + a5) + (a6 + a7));
        }
        if (ft == 15 && acc > thr) ft = s;
    }
    if (tid < F) ftout[((size_t)b * F + tid) * NPX + px] = (unsigned char)ft;
}

// ---------- pool 2x2 s2 (min fire time) + pad=1 ----------
__global__ __launch_bounds__(256) void k_pool1(const unsigned char* __restrict__ ft1,
                                               unsigned char* __restrict__ ft1p) {
    int idx = blockIdx.x * 256 + threadIdx.x;
    const int total = NB * 90 * 17 * 17;
    if (idx >= total) return;
    int xx = idx % 17, rest = idx / 17;
    int yy = rest % 17; rest /= 17;
    int c = rest % 90;  int b = rest / 90;
    int ft = 15;
    if (xx >= 1 && xx < 16 && yy >= 1 && yy < 16) {
        const unsigned char* p = ft1 + ((size_t)b * 90 + c) * 900 + (yy - 1) * 2 * 30 + (xx - 1) * 2;
        int m = p[0];
        m = min(m, (int)p[1]);
        m = min(m, (int)p[30]);
        m = min(m, (int)p[31]);
        ft = m;
    }
    ft1p[idx] = (unsigned char)ft;
}

// ---------- pool 3x3 s3 (min fire time) + pad=2 ----------
__global__ __launch_bounds__(256) void k_pool2(const unsigned char* __restrict__ ft2,
                                               unsigned char* __restrict__ ft2p) {
    int idx = blockIdx.x * 256 + threadIdx.x;
    const int total = NB * 250 * 8 * 8;
    if (idx >= total) return;
    int xx = idx % 8, rest = idx / 8;
    int yy = rest % 8; rest /= 8;
    int c = rest % 250; int b = rest / 250;
    int ft = 15;
    if (xx >= 2 && xx < 6 && yy >= 2 && yy < 6) {
        const unsigned char* p = ft2 + ((size_t)b * 250 + c) * 169 + (yy - 2) * 3 * 13 + (xx - 2) * 3;
        int m = 15;
#pragma unroll
        for (int dy = 0; dy < 3; dy++)
#pragma unroll
            for (int dx = 0; dx < 3; dx++) m = min(m, (int)p[dy * 13 + dx]);
        ft = m;
    }
    ft2p[idx] = (unsigned char)ft;
}

// ---------- conv3 (250->200, 5x5) -> pot3 dense (B,T,200,4,4) ----------
__global__ __launch_bounds__(256) void k_conv3(const unsigned char* __restrict__ ft2p,
                                               const float* __restrict__ w3,
                                               float* __restrict__ out) {
    int tid = threadIdx.x;
    int fl = tid >> 4, px = tid & 15;
    int f = blockIdx.x * 16 + fl, b = blockIdx.z;
    if (f >= 200) return;
    int oy = px >> 2, ox = px & 3;
    float acc[NT];
#pragma unroll
    for (int t = 0; t < NT; t++) acc[t] = 0.f;
    const unsigned char* fb = ft2p + (size_t)b * 250 * 64;
    const float* wf = w3 + (size_t)f * 6250;
    for (int c = 0; c < 250; c++) {
#pragma unroll
        for (int ky = 0; ky < 5; ky++) {
            const unsigned char* row = fb + c * 64 + (oy + ky) * 8 + ox;
            const float* wr = wf + c * 25 + ky * 5;
#pragma unroll
            for (int kx = 0; kx < 5; kx++) {
                int fv = row[kx];
                float w = wr[kx];
#pragma unroll
                for (int t = 0; t < NT; t++) acc[t] += (fv <= t) ? w : 0.f;
            }
        }
    }
    float* o = out + 32 + (size_t)b * NT * 3200 + f * 16 + px;
#pragma unroll
    for (int t = 0; t < NT; t++) o[(size_t)t * 3200] = acc[t];
}

// ---------- winner-take-all classification ----------
__global__ __launch_bounds__(256) void k_winner(const float* __restrict__ outp,
                                                float* __restrict__ outc) {
    int b = blockIdx.x, tid = threadIdx.x;
    const float* p14 = outp + 32 + ((size_t)b * NT + 14) * 3200;
    __shared__ float sv[256];
    __shared__ int   si[256];
    float m = 0.f;
    for (int j = tid; j < 3200; j += 256) {
        float v = p14[j];
        if (v > 0.f && v > m) m = v;
    }
    sv[tid] = m;
    __syncthreads();
    for (int s = 128; s > 0; s >>= 1) {
        if (tid < s) sv[tid] = fmaxf(sv[tid], sv[tid + s]);
        __syncthreads();
    }
    float vofs = 15.f * sv[0];
    __syncthreads();
    float bestv = 0.f; int besti = 0x3fffffff;
    for (int j = tid; j < 3200; j += 256) {
        float v = p14[j];
        float tot = (v > 0.f) ? v + vofs : 0.f;
        if (tot > bestv) { bestv = tot; besti = j; }
    }
    sv[tid] = bestv; si[tid] = besti;
    __syncthreads();
    for (int s = 128; s > 0; s >>= 1) {
        if (tid < s) {
            if (sv[tid + s] > sv[tid] || (sv[tid + s] == sv[tid] && si[tid + s] < si[tid])) {
                sv[tid] = sv[tid + s]; si[tid] = si[tid + s];
            }
        }
        __syncthreads();
    }
    if (tid == 0) {
        float mx = sv[0];
        int cls = (mx != 0.f) ? ((si[0] / 16) / 20) : -1;
        outc[b] = (float)cls;
    }
}

extern "C" void kernel_launch(void* const* d_in, const int* in_sizes, int n_in,
                              void* d_out, int out_size, void* d_ws, size_t ws_size,
                              hipStream_t stream) {
    const float* inp = (const float*)d_in[0];
    const float* w1  = (const float*)d_in[1];
    const float* w2  = (const float*)d_in[2];
    const float* w3  = (const float*)d_in[3];
    float* out = (float*)d_out;

    unsigned char* ws   = (unsigned char*)d_ws;
    unsigned char* ft0  = ws;
    unsigned char* ft1  = ft0 + 746496;
    unsigned char* ft1p = ft1 + 2592000;
    unsigned char* ft2  = ft1p + 832320;
    unsigned char* ft2p = ft2 + 1352000;
    float* wT1 = (float*)(ft2p + 512000);               // (883,90)
    float* wT2 = (float*)((unsigned char*)wT1 + 317888); // (2251,250), 16B aligned

    hipLaunchKernelGGL(k_ft0, dim3((NB * 18 * 36 * 36 + 255) / 256), dim3(256), 0, stream, inp, ft0);
    hipLaunchKernelGGL((k_tr<90, 882>),   dim3((883 * 90 + 255) / 256),   dim3(256), 0, stream, w1, wT1);
    hipLaunchKernelGGL((k_tr<250, 2250>), dim3((2251 * 250 + 255) / 256), dim3(256), 0, stream, w2, wT2);

    // conv1: TAPS=882, F=90, BLOCK=128, KW=7, OW=30, NPX=900, IH=36, IPLANE=1296, CIN=18
    hipLaunchKernelGGL((k_conv_sorted<882, 90, 128, 7, 30, 900, 36, 1296, 18>),
                       dim3(900, NB), dim3(128), 0, stream, ft0, wT1, ft1, 15.0f);
    hipLaunchKernelGGL(k_pool1, dim3((NB * 90 * 289 + 255) / 256), dim3(256), 0, stream, ft1, ft1p);
    // conv2: TAPS=2250, F=250, BLOCK=256, KW=5, OW=13, NPX=169, IH=17, IPLANE=289, CIN=90
    hipLaunchKernelGGL((k_conv_sorted<2250, 250, 256, 5, 13, 169, 17, 289, 90>),
                       dim3(169, NB), dim3(256), 0, stream, ft1p, wT2, ft2, 10.0f);
    hipLaunchKernelGGL(k_pool2, dim3((NB * 250 * 64 + 255) / 256), dim3(256), 0, stream, ft2, ft2p);
    hipLaunchKernelGGL(k_conv3, dim3(13, 1, NB), dim3(256), 0, stream, ft2p, w3, out);
    hipLaunchKernelGGL(k_winner, dim3(NB), dim3(256), 0, stream, out, out);
}

// Round 3
// 1194.519 us; speedup vs baseline: 5.1395x; 1.5909x over previous
//
#include <hip/hip_runtime.h>

#define NB 32
#define NT 15

// Workspace layout:
//  ft0  : (B,18,36,36) u8 input fire times, pad=2 baked     746496 B
//  ft1  : (B,90,30,30) u8 layer-1 fire times               2592000 B
//  ft1p : (B,90,17,17) u8 pool2x2s2 + pad=1                 832320 B
//  ft2  : (B,250,13,13) u8 layer-2 fire times              1352000 B
//  ft2p : (B,250,8,8)  u8 pool3x3s3 + pad=2                 512000 B
//  wT1  : (883,90) f32 transposed w1 + zero row             317880 B (pad to 317888)
//  wT2  : (2251,250) f32 transposed w2 + zero row          2251000 B (pad to 2251008)
//  wT3  : (6251,200) f32 transposed w3 + zero row          5000800 B
// total ~13.6 MB

// ---------- K0: input fire times (padded plane) ----------
__global__ __launch_bounds__(256) void k_ft0(const float* __restrict__ inp,
                                             unsigned char* __restrict__ ft0) {
    int idx = blockIdx.x * 256 + threadIdx.x;
    const int total = NB * 18 * 36 * 36;
    if (idx >= total) return;
    int xx = idx % 36, rest = idx / 36;
    int yy = rest % 36; rest /= 36;
    int c = rest % 18;  int b = rest / 18;
    int ft = 15;
    int x = xx - 2, y = yy - 2;
    if (x >= 0 && x < 32 && y >= 0 && y < 32) {
        int cnt = 0;
        const float* p = inp + ((size_t)(b * NT) * 18 + c) * 1024 + y * 32 + x;
#pragma unroll
        for (int t = 0; t < NT; t++) cnt += (p[(size_t)t * 18 * 1024] != 0.f);
        ft = 15 - cnt;   // cumulative wave: #ones == 15 - fire_time
    }
    ft0[idx] = (unsigned char)ft;
}

// ---------- weight transpose (OIHW -> [tap][f]) with zero pad row ----------
template<int F, int K>
__global__ __launch_bounds__(256) void k_tr(const float* __restrict__ src,
                                            float* __restrict__ dst) {
    int idx = blockIdx.x * 256 + threadIdx.x;
    const int total = (K + 1) * F;      // extra zero row at k==K (pad target)
    if (idx >= total) return;
    int k = idx / F, f = idx - k * F;
    dst[idx] = (k < K) ? src[f * K + k] : 0.f;
}

// ---------- sorted-prefix conv (fire-time output) ----------
template<int TAPS, int F, int BLOCK, int KW, int OW, int NPX, int IH, int IPLANE, int CIN>
__global__ __launch_bounds__(BLOCK) void k_conv_sorted(const unsigned char* __restrict__ ftin,
                                                       const float* __restrict__ wT,
                                                       unsigned char* __restrict__ ftout,
                                                       float thr) {
    constexpr int PADCAP = TAPS + 15 * 8;
    __shared__ unsigned char ftl[TAPS];
    __shared__ int perm[PADCAP];
    __shared__ int start[16];
    __shared__ int cur[16];
    int tid = threadIdx.x;
    int px = blockIdx.x, b = blockIdx.y;
    int oy = px / OW, ox = px - oy * OW;
    const unsigned char* base = ftin + (size_t)b * CIN * IPLANE + oy * IH + ox;

    for (int i = tid; i < TAPS; i += BLOCK) {
        int c = i / (KW * KW); int rem = i - c * (KW * KW);
        int r = rem / KW; int x = rem - r * KW;
        ftl[i] = base[c * IPLANE + r * IH + x];
    }
    if (tid < 16) cur[tid] = 0;
    __syncthreads();
    for (int i = tid; i < TAPS; i += BLOCK) {
        int v = ftl[i];
        if (v < 15) atomicAdd(&cur[v], 1);
    }
    __syncthreads();
    if (tid == 0) {
        int s = 0;
#pragma unroll
        for (int j = 0; j < 15; j++) { int c = cur[j]; start[j] = s; s += (c + 7) & ~7; }
        start[15] = s;
    }
    __syncthreads();
    int nnzp = start[15];
    if (tid < 15) cur[tid] = start[tid];
    const int zoff = TAPS * F * 4;
    for (int i = tid; i < nnzp; i += BLOCK) perm[i] = zoff;
    __syncthreads();
    for (int i = tid; i < TAPS; i += BLOCK) {
        int v = ftl[i];
        if (v < 15) { int p = atomicAdd(&cur[v], 1); perm[p] = i * (F * 4); }
    }
    __syncthreads();

    int f = tid < F ? tid : F - 1;
    const char* wb = (const char*)(wT + f);
    float acc = 0.f; int ft = 15;
    for (int s = 0; s < 15; s++) {
        int e = start[s + 1];
        for (int i = start[s]; i < e; i += 8) {
            int o0 = __builtin_amdgcn_readfirstlane(perm[i + 0]);
            int o1 = __builtin_amdgcn_readfirstlane(perm[i + 1]);
            int o2 = __builtin_amdgcn_readfirstlane(perm[i + 2]);
            int o3 = __builtin_amdgcn_readfirstlane(perm[i + 3]);
            int o4 = __builtin_amdgcn_readfirstlane(perm[i + 4]);
            int o5 = __builtin_amdgcn_readfirstlane(perm[i + 5]);
            int o6 = __builtin_amdgcn_readfirstlane(perm[i + 6]);
            int o7 = __builtin_amdgcn_readfirstlane(perm[i + 7]);
            float a0 = *(const float*)(wb + o0);
            float a1 = *(const float*)(wb + o1);
            float a2 = *(const float*)(wb + o2);
            float a3 = *(const float*)(wb + o3);
            float a4 = *(const float*)(wb + o4);
            float a5 = *(const float*)(wb + o5);
            float a6 = *(const float*)(wb + o6);
            float a7 = *(const float*)(wb + o7);
            acc += ((a0 + a1) + (a2 + a3)) + ((a4 + a5) + (a6 + a7));
        }
        if (ft == 15 && acc > thr) ft = s;
    }
    if (tid < F) ftout[((size_t)b * F + tid) * NPX + px] = (unsigned char)ft;
}

// ---------- sorted-prefix conv3: emits all 15 cumulative potentials ----------
// block=(px 0..15, b), lane=f(200). After bucket s, acc == pot3[t=s].
__global__ __launch_bounds__(256) void k_conv3s(const unsigned char* __restrict__ ft2p,
                                                const float* __restrict__ wT3,
                                                float* __restrict__ out) {
    constexpr int TAPS = 6250, F = 200, BLOCK = 256;
    constexpr int PADCAP = TAPS + 15 * 8;
    __shared__ unsigned char ftl[TAPS];
    __shared__ int perm[PADCAP];
    __shared__ int start[16];
    __shared__ int cur[16];
    int tid = threadIdx.x;
    int px = blockIdx.x, b = blockIdx.y;
    int oy = px >> 2, ox = px & 3;
    const unsigned char* base = ft2p + (size_t)b * 250 * 64 + oy * 8 + ox;

    for (int i = tid; i < TAPS; i += BLOCK) {
        int c = i / 25; int rem = i - c * 25;
        int r = rem / 5; int x = rem - r * 5;
        ftl[i] = base[c * 64 + r * 8 + x];
    }
    if (tid < 16) cur[tid] = 0;
    __syncthreads();
    for (int i = tid; i < TAPS; i += BLOCK) {
        int v = ftl[i];
        if (v < 15) atomicAdd(&cur[v], 1);
    }
    __syncthreads();
    if (tid == 0) {
        int s = 0;
#pragma unroll
        for (int j = 0; j < 15; j++) { int c = cur[j]; start[j] = s; s += (c + 7) & ~7; }
        start[15] = s;
    }
    __syncthreads();
    int nnzp = start[15];
    if (tid < 15) cur[tid] = start[tid];
    const int zoff = TAPS * F * 4;
    for (int i = tid; i < nnzp; i += BLOCK) perm[i] = zoff;
    __syncthreads();
    for (int i = tid; i < TAPS; i += BLOCK) {
        int v = ftl[i];
        if (v < 15) { int p = atomicAdd(&cur[v], 1); perm[p] = i * (F * 4); }
    }
    __syncthreads();

    int f = tid < F ? tid : F - 1;
    const char* wb = (const char*)(wT3 + f);
    float* o = out + 32 + ((size_t)b * NT) * 3200 + f * 16 + px;
    float acc = 0.f;
    for (int s = 0; s < 15; s++) {
        int e = start[s + 1];
        for (int i = start[s]; i < e; i += 8) {
            int o0 = __builtin_amdgcn_readfirstlane(perm[i + 0]);
            int o1 = __builtin_amdgcn_readfirstlane(perm[i + 1]);
            int o2 = __builtin_amdgcn_readfirstlane(perm[i + 2]);
            int o3 = __builtin_amdgcn_readfirstlane(perm[i + 3]);
            int o4 = __builtin_amdgcn_readfirstlane(perm[i + 4]);
            int o5 = __builtin_amdgcn_readfirstlane(perm[i + 5]);
            int o6 = __builtin_amdgcn_readfirstlane(perm[i + 6]);
            int o7 = __builtin_amdgcn_readfirstlane(perm[i + 7]);
            float a0 = *(const float*)(wb + o0);
            float a1 = *(const float*)(wb + o1);
            float a2 = *(const float*)(wb + o2);
            float a3 = *(const float*)(wb + o3);
            float a4 = *(const float*)(wb + o4);
            float a5 = *(const float*)(wb + o5);
            float a6 = *(const float*)(wb + o6);
            float a7 = *(const float*)(wb + o7);
            acc += ((a0 + a1) + (a2 + a3)) + ((a4 + a5) + (a6 + a7));
        }
        if (tid < F) o[(size_t)s * 3200] = acc;
    }
}

// ---------- pool 2x2 s2 (min fire time) + pad=1 ----------
__global__ __launch_bounds__(256) void k_pool1(const unsigned char* __restrict__ ft1,
                                               unsigned char* __restrict__ ft1p) {
    int idx = blockIdx.x * 256 + threadIdx.x;
    const int total = NB * 90 * 17 * 17;
    if (idx >= total) return;
    int xx = idx % 17, rest = idx / 17;
    int yy = rest % 17; rest /= 17;
    int c = rest % 90;  int b = rest / 90;
    int ft = 15;
    if (xx >= 1 && xx < 16 && yy >= 1 && yy < 16) {
        const unsigned char* p = ft1 + ((size_t)b * 90 + c) * 900 + (yy - 1) * 2 * 30 + (xx - 1) * 2;
        int m = p[0];
        m = min(m, (int)p[1]);
        m = min(m, (int)p[30]);
        m = min(m, (int)p[31]);
        ft = m;
    }
    ft1p[idx] = (unsigned char)ft;
}

// ---------- pool 3x3 s3 (min fire time) + pad=2 ----------
__global__ __launch_bounds__(256) void k_pool2(const unsigned char* __restrict__ ft2,
                                               unsigned char* __restrict__ ft2p) {
    int idx = blockIdx.x * 256 + threadIdx.x;
    const int total = NB * 250 * 8 * 8;
    if (idx >= total) return;
    int xx = idx % 8, rest = idx / 8;
    int yy = rest % 8; rest /= 8;
    int c = rest % 250; int b = rest / 250;
    int ft = 15;
    if (xx >= 2 && xx < 6 && yy >= 2 && yy < 6) {
        const unsigned char* p = ft2 + ((size_t)b * 250 + c) * 169 + (yy - 2) * 3 * 13 + (xx - 2) * 3;
        int m = 15;
#pragma unroll
        for (int dy = 0; dy < 3; dy++)
#pragma unroll
            for (int dx = 0; dx < 3; dx++) m = min(m, (int)p[dy * 13 + dx]);
        ft = m;
    }
    ft2p[idx] = (unsigned char)ft;
}

// ---------- winner-take-all classification ----------
__global__ __launch_bounds__(256) void k_winner(const float* __restrict__ outp,
                                                float* __restrict__ outc) {
    int b = blockIdx.x, tid = threadIdx.x;
    const float* p14 = outp + 32 + ((size_t)b * NT + 14) * 3200;
    __shared__ float sv[256];
    __shared__ int   si[256];
    float m = 0.f;
    for (int j = tid; j < 3200; j += 256) {
        float v = p14[j];
        if (v > 0.f && v > m) m = v;
    }
    sv[tid] = m;
    __syncthreads();
    for (int s = 128; s > 0; s >>= 1) {
        if (tid < s) sv[tid] = fmaxf(sv[tid], sv[tid + s]);
        __syncthreads();
    }
    float vofs = 15.f * sv[0];
    __syncthreads();
    float bestv = 0.f; int besti = 0x3fffffff;
    for (int j = tid; j < 3200; j += 256) {
        float v = p14[j];
        float tot = (v > 0.f) ? v + vofs : 0.f;
        if (tot > bestv) { bestv = tot; besti = j; }
    }
    sv[tid] = bestv; si[tid] = besti;
    __syncthreads();
    for (int s = 128; s > 0; s >>= 1) {
        if (tid < s) {
            if (sv[tid + s] > sv[tid] || (sv[tid + s] == sv[tid] && si[tid + s] < si[tid])) {
                sv[tid] = sv[tid + s]; si[tid] = si[tid + s];
            }
        }
        __syncthreads();
    }
    if (tid == 0) {
        float mx = sv[0];
        int cls = (mx != 0.f) ? ((si[0] / 16) / 20) : -1;
        outc[b] = (float)cls;
    }
}

extern "C" void kernel_launch(void* const* d_in, const int* in_sizes, int n_in,
                              void* d_out, int out_size, void* d_ws, size_t ws_size,
                              hipStream_t stream) {
    const float* inp = (const float*)d_in[0];
    const float* w1  = (const float*)d_in[1];
    const float* w2  = (const float*)d_in[2];
    const float* w3  = (const float*)d_in[3];
    float* out = (float*)d_out;

    unsigned char* ws   = (unsigned char*)d_ws;
    unsigned char* ft0  = ws;
    unsigned char* ft1  = ft0 + 746496;
    unsigned char* ft1p = ft1 + 2592000;
    unsigned char* ft2  = ft1p + 832320;
    unsigned char* ft2p = ft2 + 1352000;
    float* wT1 = (float*)(ft2p + 512000);                 // (883,90)
    float* wT2 = (float*)((unsigned char*)wT1 + 317888);  // (2251,250)
    float* wT3 = (float*)((unsigned char*)wT2 + 2251008); // (6251,200)

    hipLaunchKernelGGL(k_ft0, dim3((NB * 18 * 36 * 36 + 255) / 256), dim3(256), 0, stream, inp, ft0);
    hipLaunchKernelGGL((k_tr<90, 882>),    dim3((883 * 90 + 255) / 256),    dim3(256), 0, stream, w1, wT1);
    hipLaunchKernelGGL((k_tr<250, 2250>),  dim3((2251 * 250 + 255) / 256),  dim3(256), 0, stream, w2, wT2);
    hipLaunchKernelGGL((k_tr<200, 6250>),  dim3((6251 * 200 + 255) / 256),  dim3(256), 0, stream, w3, wT3);

    hipLaunchKernelGGL((k_conv_sorted<882, 90, 128, 7, 30, 900, 36, 1296, 18>),
                       dim3(900, NB), dim3(128), 0, stream, ft0, wT1, ft1, 15.0f);
    hipLaunchKernelGGL(k_pool1, dim3((NB * 90 * 289 + 255) / 256), dim3(256), 0, stream, ft1, ft1p);
    hipLaunchKernelGGL((k_conv_sorted<2250, 250, 256, 5, 13, 169, 17, 289, 90>),
                       dim3(169, NB), dim3(256), 0, stream, ft1p, wT2, ft2, 10.0f);
    hipLaunchKernelGGL(k_pool2, dim3((NB * 250 * 64 + 255) / 256), dim3(256), 0, stream, ft2, ft2p);
    hipLaunchKernelGGL(k_conv3s, dim3(16, NB), dim3(256), 0, stream, ft2p, wT3, out);
    hipLaunchKernelGGL(k_winner, dim3(NB), dim3(256), 0, stream, out, out);
}

// Round 4
// 861.417 us; speedup vs baseline: 7.1269x; 1.3867x over previous
//
#include <hip/hip_runtime.h>

#define NB 32
#define NT 15

// Workspace layout:
//  ft0  : (B,18,36,36) u8 input fire times, pad=2 baked     746496 B
//  ft1  : (B,90,30,30) u8 layer-1 fire times               2592000 B
//  ft1p : (B,90,17,17) u8 pool2x2s2 + pad=1                 832320 B
//  ft2  : (B,250,13,13) u8 layer-2 fire times              1352000 B
//  ft2p : (B,250,8,8)  u8 pool3x3s3 + pad=2                 512000 B
//  wT1  : (883,90) f32 transposed w1 + zero row             317880 B (pad to 317888)
//  wT2  : (2251,250) f32 transposed w2 + zero row          2251000 B (pad to 2251008)
//  wT3  : (6251,200) f32 transposed w3 + zero row          5000800 B
// total ~13.6 MB

// ---------- K0: input fire times (padded plane) ----------
__global__ __launch_bounds__(256) void k_ft0(const float* __restrict__ inp,
                                             unsigned char* __restrict__ ft0) {
    int idx = blockIdx.x * 256 + threadIdx.x;
    const int total = NB * 18 * 36 * 36;
    if (idx >= total) return;
    int xx = idx % 36, rest = idx / 36;
    int yy = rest % 36; rest /= 36;
    int c = rest % 18;  int b = rest / 18;
    int ft = 15;
    int x = xx - 2, y = yy - 2;
    if (x >= 0 && x < 32 && y >= 0 && y < 32) {
        int cnt = 0;
        const float* p = inp + ((size_t)(b * NT) * 18 + c) * 1024 + y * 32 + x;
#pragma unroll
        for (int t = 0; t < NT; t++) cnt += (p[(size_t)t * 18 * 1024] != 0.f);
        ft = 15 - cnt;   // cumulative wave: #ones == 15 - fire_time
    }
    ft0[idx] = (unsigned char)ft;
}

// ---------- weight transpose (OIHW -> [tap][f]) with zero pad row ----------
template<int F, int K>
__global__ __launch_bounds__(256) void k_tr(const float* __restrict__ src,
                                            float* __restrict__ dst) {
    int idx = blockIdx.x * 256 + threadIdx.x;
    const int total = (K + 1) * F;      // extra zero row at k==K (pad target)
    if (idx >= total) return;
    int k = idx / F, f = idx - k * F;
    dst[idx] = (k < K) ? src[f * K + k] : 0.f;
}

// ---------- sorted-prefix conv (fire-time output), early-exit when wave done ----------
template<int TAPS, int F, int BLOCK, int KW, int OW, int NPX, int IH, int IPLANE, int CIN>
__global__ __launch_bounds__(BLOCK) void k_conv_sorted(const unsigned char* __restrict__ ftin,
                                                       const float* __restrict__ wT,
                                                       unsigned char* __restrict__ ftout,
                                                       float thr) {
    constexpr int PADCAP = TAPS + 15 * 8;
    __shared__ unsigned char ftl[TAPS];
    __shared__ __align__(16) int perm[PADCAP];
    __shared__ int start[16];
    __shared__ int cur[16];
    int tid = threadIdx.x;
    int px = blockIdx.x, b = blockIdx.y;
    int oy = px / OW, ox = px - oy * OW;
    const unsigned char* base = ftin + (size_t)b * CIN * IPLANE + oy * IH + ox;

    for (int i = tid; i < TAPS; i += BLOCK) {
        int c = i / (KW * KW); int rem = i - c * (KW * KW);
        int r = rem / KW; int x = rem - r * KW;
        ftl[i] = base[c * IPLANE + r * IH + x];
    }
    if (tid < 16) cur[tid] = 0;
    __syncthreads();
    for (int i = tid; i < TAPS; i += BLOCK) {
        int v = ftl[i];
        if (v < 15) atomicAdd(&cur[v], 1);
    }
    __syncthreads();
    if (tid == 0) {
        int s = 0;
#pragma unroll
        for (int j = 0; j < 15; j++) { int c = cur[j]; start[j] = s; s += (c + 7) & ~7; }
        start[15] = s;
    }
    __syncthreads();
    int nnzp = start[15];
    if (tid < 15) cur[tid] = start[tid];
    const int zoff = TAPS * F * 4;
    for (int i = tid; i < nnzp; i += BLOCK) perm[i] = zoff;
    __syncthreads();
    for (int i = tid; i < TAPS; i += BLOCK) {
        int v = ftl[i];
        if (v < 15) { int p = atomicAdd(&cur[v], 1); perm[p] = i * (F * 4); }
    }
    __syncthreads();

    int f = tid < F ? tid : F - 1;
    const char* wb = (const char*)(wT + f);
    float acc = 0.f; int ft = 15;
    for (int s = 0; s < 15; s++) {
        int e = start[s + 1];
        for (int i = start[s]; i < e; i += 8) {
            int4 p0 = *(const int4*)(perm + i);
            int4 p1 = *(const int4*)(perm + i + 4);
            int o0 = __builtin_amdgcn_readfirstlane(p0.x);
            int o1 = __builtin_amdgcn_readfirstlane(p0.y);
            int o2 = __builtin_amdgcn_readfirstlane(p0.z);
            int o3 = __builtin_amdgcn_readfirstlane(p0.w);
            int o4 = __builtin_amdgcn_readfirstlane(p1.x);
            int o5 = __builtin_amdgcn_readfirstlane(p1.y);
            int o6 = __builtin_amdgcn_readfirstlane(p1.z);
            int o7 = __builtin_amdgcn_readfirstlane(p1.w);
            float a0 = *(const float*)(wb + o0);
            float a1 = *(const float*)(wb + o1);
            float a2 = *(const float*)(wb + o2);
            float a3 = *(const float*)(wb + o3);
            float a4 = *(const float*)(wb + o4);
            float a5 = *(const float*)(wb + o5);
            float a6 = *(const float*)(wb + o6);
            float a7 = *(const float*)(wb + o7);
            acc += ((a0 + a1) + (a2 + a3)) + ((a4 + a5) + (a6 + a7));
        }
        if (ft == 15 && acc > thr) ft = s;
        if (__all(ft != 15)) break;   // exact: every lane has recorded its crossing
    }
    if (tid < F) ftout[((size_t)b * F + tid) * NPX + px] = (unsigned char)ft;
}

// ---------- sorted-prefix conv3: emits all 15 cumulative potentials ----------
__global__ __launch_bounds__(256) void k_conv3s(const unsigned char* __restrict__ ft2p,
                                                const float* __restrict__ wT3,
                                                float* __restrict__ out) {
    constexpr int TAPS = 6250, F = 200, BLOCK = 256;
    constexpr int PADCAP = TAPS + 15 * 8;
    __shared__ unsigned char ftl[TAPS];
    __shared__ __align__(16) int perm[PADCAP];
    __shared__ int start[16];
    __shared__ int cur[16];
    int tid = threadIdx.x;
    int px = blockIdx.x, b = blockIdx.y;
    int oy = px >> 2, ox = px & 3;
    const unsigned char* base = ft2p + (size_t)b * 250 * 64 + oy * 8 + ox;

    for (int i = tid; i < TAPS; i += BLOCK) {
        int c = i / 25; int rem = i - c * 25;
        int r = rem / 5; int x = rem - r * 5;
        ftl[i] = base[c * 64 + r * 8 + x];
    }
    if (tid < 16) cur[tid] = 0;
    __syncthreads();
    for (int i = tid; i < TAPS; i += BLOCK) {
        int v = ftl[i];
        if (v < 15) atomicAdd(&cur[v], 1);
    }
    __syncthreads();
    if (tid == 0) {
        int s = 0;
#pragma unroll
        for (int j = 0; j < 15; j++) { int c = cur[j]; start[j] = s; s += (c + 7) & ~7; }
        start[15] = s;
    }
    __syncthreads();
    int nnzp = start[15];
    if (tid < 15) cur[tid] = start[tid];
    const int zoff = TAPS * F * 4;
    for (int i = tid; i < nnzp; i += BLOCK) perm[i] = zoff;
    __syncthreads();
    for (int i = tid; i < TAPS; i += BLOCK) {
        int v = ftl[i];
        if (v < 15) { int p = atomicAdd(&cur[v], 1); perm[p] = i * (F * 4); }
    }
    __syncthreads();

    int f = tid < F ? tid : F - 1;
    const char* wb = (const char*)(wT3 + f);
    float* o = out + 32 + ((size_t)b * NT) * 3200 + f * 16 + px;
    float acc = 0.f;
    for (int s = 0; s < 15; s++) {
        int e = start[s + 1];
        for (int i = start[s]; i < e; i += 8) {
            int4 p0 = *(const int4*)(perm + i);
            int4 p1 = *(const int4*)(perm + i + 4);
            int o0 = __builtin_amdgcn_readfirstlane(p0.x);
            int o1 = __builtin_amdgcn_readfirstlane(p0.y);
            int o2 = __builtin_amdgcn_readfirstlane(p0.z);
            int o3 = __builtin_amdgcn_readfirstlane(p0.w);
            int o4 = __builtin_amdgcn_readfirstlane(p1.x);
            int o5 = __builtin_amdgcn_readfirstlane(p1.y);
            int o6 = __builtin_amdgcn_readfirstlane(p1.z);
            int o7 = __builtin_amdgcn_readfirstlane(p1.w);
            float a0 = *(const float*)(wb + o0);
            float a1 = *(const float*)(wb + o1);
            float a2 = *(const float*)(wb + o2);
            float a3 = *(const float*)(wb + o3);
            float a4 = *(const float*)(wb + o4);
            float a5 = *(const float*)(wb + o5);
            float a6 = *(const float*)(wb + o6);
            float a7 = *(const float*)(wb + o7);
            acc += ((a0 + a1) + (a2 + a3)) + ((a4 + a5) + (a6 + a7));
        }
        if (tid < F) o[(size_t)s * 3200] = acc;
    }
}

// ---------- pool 2x2 s2 (min fire time) + pad=1 ----------
__global__ __launch_bounds__(256) void k_pool1(const unsigned char* __restrict__ ft1,
                                               unsigned char* __restrict__ ft1p) {
    int idx = blockIdx.x * 256 + threadIdx.x;
    const int total = NB * 90 * 17 * 17;
    if (idx >= total) return;
    int xx = idx % 17, rest = idx / 17;
    int yy = rest % 17; rest /= 17;
    int c = rest % 90;  int b = rest / 90;
    int ft = 15;
    if (xx >= 1 && xx < 16 && yy >= 1 && yy < 16) {
        const unsigned char* p = ft1 + ((size_t)b * 90 + c) * 900 + (yy - 1) * 2 * 30 + (xx - 1) * 2;
        int m = p[0];
        m = min(m, (int)p[1]);
        m = min(m, (int)p[30]);
        m = min(m, (int)p[31]);
        ft = m;
    }
    ft1p[idx] = (unsigned char)ft;
}

// ---------- pool 3x3 s3 (min fire time) + pad=2 ----------
__global__ __launch_bounds__(256) void k_pool2(const unsigned char* __restrict__ ft2,
                                               unsigned char* __restrict__ ft2p) {
    int idx = blockIdx.x * 256 + threadIdx.x;
    const int total = NB * 250 * 8 * 8;
    if (idx >= total) return;
    int xx = idx % 8, rest = idx / 8;
    int yy = rest % 8; rest /= 8;
    int c = rest % 250; int b = rest / 250;
    int ft = 15;
    if (xx >= 2 && xx < 6 && yy >= 2 && yy < 6) {
        const unsigned char* p = ft2 + ((size_t)b * 250 + c) * 169 + (yy - 2) * 3 * 13 + (xx - 2) * 3;
        int m = 15;
#pragma unroll
        for (int dy = 0; dy < 3; dy++)
#pragma unroll
            for (int dx = 0; dx < 3; dx++) m = min(m, (int)p[dy * 13 + dx]);
        ft = m;
    }
    ft2p[idx] = (unsigned char)ft;
}

// ---------- winner-take-all classification ----------
__global__ __launch_bounds__(256) void k_winner(const float* __restrict__ outp,
                                                float* __restrict__ outc) {
    int b = blockIdx.x, tid = threadIdx.x;
    const float* p14 = outp + 32 + ((size_t)b * NT + 14) * 3200;
    __shared__ float sv[256];
    __shared__ int   si[256];
    float m = 0.f;
    for (int j = tid; j < 3200; j += 256) {
        float v = p14[j];
        if (v > 0.f && v > m) m = v;
    }
    sv[tid] = m;
    __syncthreads();
    for (int s = 128; s > 0; s >>= 1) {
        if (tid < s) sv[tid] = fmaxf(sv[tid], sv[tid + s]);
        __syncthreads();
    }
    float vofs = 15.f * sv[0];
    __syncthreads();
    float bestv = 0.f; int besti = 0x3fffffff;
    for (int j = tid; j < 3200; j += 256) {
        float v = p14[j];
        float tot = (v > 0.f) ? v + vofs : 0.f;
        if (tot > bestv) { bestv = tot; besti = j; }
    }
    sv[tid] = bestv; si[tid] = besti;
    __syncthreads();
    for (int s = 128; s > 0; s >>= 1) {
        if (tid < s) {
            if (sv[tid + s] > sv[tid] || (sv[tid + s] == sv[tid] && si[tid + s] < si[tid])) {
                sv[tid] = sv[tid + s]; si[tid] = si[tid + s];
            }
        }
        __syncthreads();
    }
    if (tid == 0) {
        float mx = sv[0];
        int cls = (mx != 0.f) ? ((si[0] / 16) / 20) : -1;
        outc[b] = (float)cls;
    }
}

extern "C" void kernel_launch(void* const* d_in, const int* in_sizes, int n_in,
                              void* d_out, int out_size, void* d_ws, size_t ws_size,
                              hipStream_t stream) {
    const float* inp = (const float*)d_in[0];
    const float* w1  = (const float*)d_in[1];
    const float* w2  = (const float*)d_in[2];
    const float* w3  = (const float*)d_in[3];
    float* out = (float*)d_out;

    unsigned char* ws   = (unsigned char*)d_ws;
    unsigned char* ft0  = ws;
    unsigned char* ft1  = ft0 + 746496;
    unsigned char* ft1p = ft1 + 2592000;
    unsigned char* ft2  = ft1p + 832320;
    unsigned char* ft2p = ft2 + 1352000;
    float* wT1 = (float*)(ft2p + 512000);                 // (883,90)
    float* wT2 = (float*)((unsigned char*)wT1 + 317888);  // (2251,250)
    float* wT3 = (float*)((unsigned char*)wT2 + 2251008); // (6251,200)

    hipLaunchKernelGGL(k_ft0, dim3((NB * 18 * 36 * 36 + 255) / 256), dim3(256), 0, stream, inp, ft0);
    hipLaunchKernelGGL((k_tr<90, 882>),    dim3((883 * 90 + 255) / 256),    dim3(256), 0, stream, w1, wT1);
    hipLaunchKernelGGL((k_tr<250, 2250>),  dim3((2251 * 250 + 255) / 256),  dim3(256), 0, stream, w2, wT2);
    hipLaunchKernelGGL((k_tr<200, 6250>),  dim3((6251 * 200 + 255) / 256),  dim3(256), 0, stream, w3, wT3);

    hipLaunchKernelGGL((k_conv_sorted<882, 90, 128, 7, 30, 900, 36, 1296, 18>),
                       dim3(900, NB), dim3(128), 0, stream, ft0, wT1, ft1, 15.0f);
    hipLaunchKernelGGL(k_pool1, dim3((NB * 90 * 289 + 255) / 256), dim3(256), 0, stream, ft1, ft1p);
    hipLaunchKernelGGL((k_conv_sorted<2250, 250, 256, 5, 13, 169, 17, 289, 90>),
                       dim3(169, NB), dim3(256), 0, stream, ft1p, wT2, ft2, 10.0f);
    hipLaunchKernelGGL(k_pool2, dim3((NB * 250 * 64 + 255) / 256), dim3(256), 0, stream, ft2, ft2p);
    hipLaunchKernelGGL(k_conv3s, dim3(16, NB), dim3(256), 0, stream, ft2p, wT3, out);
    hipLaunchKernelGGL(k_winner, dim3(NB), dim3(256), 0, stream, out, out);
}

// Round 5
// 367.932 us; speedup vs baseline: 16.6858x; 2.3412x over previous
//
#include <hip/hip_runtime.h>

#define NB 32
#define NT 15

// Workspace layout (byte offsets):
//  ft0  : 0        (B,18,36,36) u8 input fire times, pad=2      746496
//  ft1  : 746496   (B,90,30,30) u8 layer-1 fire times          2592000
//  ft1p : 3338496  (B,90,17,17) u8 pool2x2s2 + pad=1            832320
//  ft2  : 4170816  (B,250,13,13) u8 layer-2 fire times         1352000
//  ft2p : 5522816  (B,250,8,8)  u8 pool3x3s3 + pad=2            512000
//  wT1  : 6034816  (883,90) f32 w1^T + zero row                 317888
//  wT2  : 6352704  (2251,250) f32 w2^T + zero row              2251008
//  wT3  : 8603712  (6251,200) f32 w3^T + zero row              5000832
//  W2s  : 13604544 (256) f32 col sums of wT2                      1024
//  W3s  : 13605568 (16,200) f32 per-px valid-tap col sums of wT3 12800
// total ~13.62 MB

// ---------- zero the weight-sum buffers (3456 floats) ----------
__global__ __launch_bounds__(256) void k_zero(float* __restrict__ p) {
    int idx = blockIdx.x * 256 + threadIdx.x;
    if (idx < 3456) p[idx] = 0.f;
}

// ---------- K0: input fire times (padded plane) ----------
__global__ __launch_bounds__(256) void k_ft0(const float* __restrict__ inp,
                                             unsigned char* __restrict__ ft0) {
    int idx = blockIdx.x * 256 + threadIdx.x;
    const int total = NB * 18 * 36 * 36;
    if (idx >= total) return;
    int xx = idx % 36, rest = idx / 36;
    int yy = rest % 36; rest /= 36;
    int c = rest % 18;  int b = rest / 18;
    int ft = 15;
    int x = xx - 2, y = yy - 2;
    if (x >= 0 && x < 32 && y >= 0 && y < 32) {
        int cnt = 0;
        const float* p = inp + ((size_t)(b * NT) * 18 + c) * 1024 + y * 32 + x;
#pragma unroll
        for (int t = 0; t < NT; t++) cnt += (p[(size_t)t * 18 * 1024] != 0.f);
        ft = 15 - cnt;   // cumulative wave: #ones == 15 - fire_time
    }
    ft0[idx] = (unsigned char)ft;
}

// ---------- weight transpose (OIHW -> [tap][f]) with zero pad row ----------
template<int F, int K>
__global__ __launch_bounds__(256) void k_tr(const float* __restrict__ src,
                                            float* __restrict__ dst) {
    int idx = blockIdx.x * 256 + threadIdx.x;
    const int total = (K + 1) * F;
    if (idx >= total) return;
    int k = idx / F, f = idx - k * F;
    dst[idx] = (k < K) ? src[f * K + k] : 0.f;
}

// ---------- column sums of wT2 -> W2s[250] ----------
__global__ __launch_bounds__(256) void k_colsum2(const float* __restrict__ wT2,
                                                 float* __restrict__ W2s) {
    int tid = threadIdx.x;
    int f = tid < 250 ? tid : 249;
    int k0 = blockIdx.x * 150;
    float acc = 0.f;
    for (int k = k0; k < k0 + 150; k++) acc += wT2[(size_t)k * 250 + f];
    if (tid < 250) atomicAdd(&W2s[tid], acc);
}

// ---------- per-px valid-tap column sums of wT3 -> W3s[16][200] ----------
__global__ __launch_bounds__(256) void k_w3s(const float* __restrict__ wT3,
                                             float* __restrict__ W3s) {
    int tid = threadIdx.x;
    int f = tid < 200 ? tid : 199;
    int px = blockIdx.x, ch = blockIdx.y;       // 16 px, 10 channel chunks of 25
    int oy = px >> 2, ox = px & 3;
    int r0 = max(0, 2 - oy), r1 = min(4, 5 - oy);
    int x0 = max(0, 2 - ox), x1 = min(4, 5 - ox);
    float acc = 0.f;
    for (int c = ch * 25; c < ch * 25 + 25; c++)
        for (int r = r0; r <= r1; r++)
            for (int x = x0; x <= x1; x++)
                acc += wT3[(size_t)(c * 25 + r * 5 + x) * 200 + f];
    if (tid < 200) atomicAdd(&W3s[px * 200 + tid], acc);
}

// ---------- sorted-prefix conv1 (fire-time output), early-exit ----------
template<int TAPS, int F, int BLOCK, int KW, int OW, int NPX, int IH, int IPLANE, int CIN>
__global__ __launch_bounds__(BLOCK) void k_conv_sorted(const unsigned char* __restrict__ ftin,
                                                       const float* __restrict__ wT,
                                                       unsigned char* __restrict__ ftout,
                                                       float thr) {
    constexpr int PADCAP = TAPS + 15 * 8;
    __shared__ unsigned char ftl[TAPS];
    __shared__ __align__(16) int perm[PADCAP];
    __shared__ int start[16];
    __shared__ int cur[16];
    int tid = threadIdx.x;
    int px = blockIdx.x, b = blockIdx.y;
    int oy = px / OW, ox = px - oy * OW;
    const unsigned char* base = ftin + (size_t)b * CIN * IPLANE + oy * IH + ox;

    for (int i = tid; i < TAPS; i += BLOCK) {
        int c = i / (KW * KW); int rem = i - c * (KW * KW);
        int r = rem / KW; int x = rem - r * KW;
        ftl[i] = base[c * IPLANE + r * IH + x];
    }
    if (tid < 16) cur[tid] = 0;
    __syncthreads();
    for (int i = tid; i < TAPS; i += BLOCK) {
        int v = ftl[i];
        if (v < 15) atomicAdd(&cur[v], 1);
    }
    __syncthreads();
    if (tid == 0) {
        int s = 0;
#pragma unroll
        for (int j = 0; j < 15; j++) { int c = cur[j]; start[j] = s; s += (c + 7) & ~7; }
        start[15] = s;
    }
    __syncthreads();
    int nnzp = start[15];
    if (tid < 15) cur[tid] = start[tid];
    const int zoff = TAPS * F * 4;
    for (int i = tid; i < nnzp; i += BLOCK) perm[i] = zoff;
    __syncthreads();
    for (int i = tid; i < TAPS; i += BLOCK) {
        int v = ftl[i];
        if (v < 15) { int p = atomicAdd(&cur[v], 1); perm[p] = i * (F * 4); }
    }
    __syncthreads();

    int f = tid < F ? tid : F - 1;
    const char* wb = (const char*)(wT + f);
    float acc = 0.f; int ft = 15;
    for (int s = 0; s < 15; s++) {
        int e = start[s + 1];
        for (int i = start[s]; i < e; i += 8) {
            int4 p0 = *(const int4*)(perm + i);
            int4 p1 = *(const int4*)(perm + i + 4);
            int o0 = __builtin_amdgcn_readfirstlane(p0.x);
            int o1 = __builtin_amdgcn_readfirstlane(p0.y);
            int o2 = __builtin_amdgcn_readfirstlane(p0.z);
            int o3 = __builtin_amdgcn_readfirstlane(p0.w);
            int o4 = __builtin_amdgcn_readfirstlane(p1.x);
            int o5 = __builtin_amdgcn_readfirstlane(p1.y);
            int o6 = __builtin_amdgcn_readfirstlane(p1.z);
            int o7 = __builtin_amdgcn_readfirstlane(p1.w);
            float a0 = *(const float*)(wb + o0);
            float a1 = *(const float*)(wb + o1);
            float a2 = *(const float*)(wb + o2);
            float a3 = *(const float*)(wb + o3);
            float a4 = *(const float*)(wb + o4);
            float a5 = *(const float*)(wb + o5);
            float a6 = *(const float*)(wb + o6);
            float a7 = *(const float*)(wb + o7);
            acc += ((a0 + a1) + (a2 + a3)) + ((a4 + a5) + (a6 + a7));
        }
        if (ft == 15 && acc > thr) ft = s;
        if (__all(ft != 15)) break;
    }
    if (tid < F) ftout[((size_t)b * F + tid) * NPX + px] = (unsigned char)ft;
}

// ---------- conv2 complement walk: pot_t = W_f - sum_{ft>t} w ----------
__global__ __launch_bounds__(256) void k_conv2c(const unsigned char* __restrict__ ft1p,
                                                const float* __restrict__ wT2,
                                                const float* __restrict__ W2s,
                                                unsigned char* __restrict__ ft2) {
    constexpr int TAPS = 2250, F = 250, BLOCK = 256;
    constexpr int PADCAP = TAPS + 15 * 8;
    __shared__ unsigned char ftl[TAPS];
    __shared__ __align__(16) int perm[PADCAP];
    __shared__ int start[16];
    __shared__ int cur[16];
    int tid = threadIdx.x;
    int px = blockIdx.x, b = blockIdx.y;
    int oy = px / 13, ox = px - oy * 13;
    const unsigned char* base = ft1p + (size_t)b * 90 * 289 + oy * 17 + ox;

    for (int i = tid; i < TAPS; i += BLOCK) {
        int c = i / 25; int rem = i - c * 25;
        int r = rem / 5; int x = rem - r * 5;
        ftl[i] = base[c * 289 + r * 17 + x];
    }
    if (tid < 16) cur[tid] = 0;
    __syncthreads();
    // histogram complement only: buckets j=0..14 hold ft = j+1 (15 = never)
    for (int i = tid; i < TAPS; i += BLOCK) {
        int v = ftl[i];
        if (v >= 1) atomicAdd(&cur[v - 1], 1);
    }
    __syncthreads();
    if (tid == 0) {
        int s = 0;
#pragma unroll
        for (int j = 0; j < 15; j++) { int c = cur[j]; start[j] = s; s += (c + 7) & ~7; }
        start[15] = s;
    }
    __syncthreads();
    int nnzp = start[15];
    if (tid < 15) cur[tid] = start[tid];
    const int zoff = TAPS * F * 4;
    for (int i = tid; i < nnzp; i += BLOCK) perm[i] = zoff;
    __syncthreads();
    for (int i = tid; i < TAPS; i += BLOCK) {
        int v = ftl[i];
        if (v >= 1) { int p = atomicAdd(&cur[v - 1], 1); perm[p] = i * (F * 4); }
    }
    __syncthreads();

    int f = tid < F ? tid : F - 1;
    const char* wb = (const char*)(wT2 + f);
    float W = W2s[f];
    float R = 0.f; int ft = 15;
    // walk t = 14 .. 0; bucket j holds ft = j+1; after bucket j, R = R_{t=j}
    for (int j = 14; j >= 0; j--) {
        int e = start[j + 1];
        for (int i = start[j]; i < e; i += 8) {
            int4 p0 = *(const int4*)(perm + i);
            int4 p1 = *(const int4*)(perm + i + 4);
            int o0 = __builtin_amdgcn_readfirstlane(p0.x);
            int o1 = __builtin_amdgcn_readfirstlane(p0.y);
            int o2 = __builtin_amdgcn_readfirstlane(p0.z);
            int o3 = __builtin_amdgcn_readfirstlane(p0.w);
            int o4 = __builtin_amdgcn_readfirstlane(p1.x);
            int o5 = __builtin_amdgcn_readfirstlane(p1.y);
            int o6 = __builtin_amdgcn_readfirstlane(p1.z);
            int o7 = __builtin_amdgcn_readfirstlane(p1.w);
            float a0 = *(const float*)(wb + o0);
            float a1 = *(const float*)(wb + o1);
            float a2 = *(const float*)(wb + o2);
            float a3 = *(const float*)(wb + o3);
            float a4 = *(const float*)(wb + o4);
            float a5 = *(const float*)(wb + o5);
            float a6 = *(const float*)(wb + o6);
            float a7 = *(const float*)(wb + o7);
            R += ((a0 + a1) + (a2 + a3)) + ((a4 + a5) + (a6 + a7));
        }
        float pot = W - R;           // pot at t = j
        if (pot > 10.0f) ft = j;     // walking downward -> final ft = smallest t
        else if (__all(pot <= 10.0f)) break;   // no lane can fire earlier
    }
    if (tid < F) ft2[((size_t)b * F + tid) * 169 + px] = (unsigned char)ft;
}

// ---------- conv3 complement walk over VALID taps; stores all 15 pots ----------
__global__ __launch_bounds__(256) void k_conv3c(const unsigned char* __restrict__ ft2p,
                                                const float* __restrict__ wT3,
                                                const float* __restrict__ W3s,
                                                float* __restrict__ out) {
    constexpr int F = 200, BLOCK = 256, MAXV = 4000;
    constexpr int PADCAP = MAXV + 15 * 8;
    __shared__ unsigned char ftl[MAXV];
    __shared__ __align__(16) int perm[PADCAP];
    __shared__ int start[16];
    __shared__ int cur[16];
    int tid = threadIdx.x;
    int px = blockIdx.x, b = blockIdx.y;
    int oy = px >> 2, ox = px & 3;
    int r0 = max(0, 2 - oy), r1 = min(4, 5 - oy);
    int x0 = max(0, 2 - ox), x1 = min(4, 5 - ox);
    int VR = r1 - r0 + 1, VC = x1 - x0 + 1;
    int NV = 250 * VR * VC;
    const unsigned char* base = ft2p + (size_t)b * 250 * 64;

    for (int i = tid; i < NV; i += BLOCK) {
        int c = i / (VR * VC); int rem = i - c * (VR * VC);
        int r = r0 + rem / VC; int x = x0 + rem % VC;
        ftl[i] = base[c * 64 + (oy + r) * 8 + (ox + x)];
        perm[i] = (c * 25 + r * 5 + x) * (F * 4);   // stash tap row offset
    }
    if (tid < 16) cur[tid] = 0;
    __syncthreads();
    for (int i = tid; i < NV; i += BLOCK) {
        int v = ftl[i];
        if (v >= 1) atomicAdd(&cur[v - 1], 1);
    }
    __syncthreads();
    __shared__ int rowoff[MAXV];   // copy of tap offsets (perm gets overwritten)
    for (int i = tid; i < NV; i += BLOCK) rowoff[i] = perm[i];
    __syncthreads();
    if (tid == 0) {
        int s = 0;
#pragma unroll
        for (int j = 0; j < 15; j++) { int c = cur[j]; start[j] = s; s += (c + 7) & ~7; }
        start[15] = s;
    }
    __syncthreads();
    int nnzp = start[15];
    if (tid < 15) cur[tid] = start[tid];
    const int zoff = 6250 * F * 4;
    for (int i = tid; i < nnzp; i += BLOCK) perm[i] = zoff;
    __syncthreads();
    for (int i = tid; i < NV; i += BLOCK) {
        int v = ftl[i];
        if (v >= 1) { int p = atomicAdd(&cur[v - 1], 1); perm[p] = rowoff[i]; }
    }
    __syncthreads();

    int f = tid < F ? tid : F - 1;
    const char* wb = (const char*)(wT3 + f);
    float W = W3s[px * F + f];
    float* o = out + 32 + ((size_t)b * NT) * 3200 + f * 16 + px;
    float R = 0.f;
    for (int j = 14; j >= 0; j--) {
        int e = start[j + 1];
        for (int i = start[j]; i < e; i += 8) {
            int4 p0 = *(const int4*)(perm + i);
            int4 p1 = *(const int4*)(perm + i + 4);
            int o0 = __builtin_amdgcn_readfirstlane(p0.x);
            int o1 = __builtin_amdgcn_readfirstlane(p0.y);
            int o2 = __builtin_amdgcn_readfirstlane(p0.z);
            int o3 = __builtin_amdgcn_readfirstlane(p0.w);
            int o4 = __builtin_amdgcn_readfirstlane(p1.x);
            int o5 = __builtin_amdgcn_readfirstlane(p1.y);
            int o6 = __builtin_amdgcn_readfirstlane(p1.z);
            int o7 = __builtin_amdgcn_readfirstlane(p1.w);
            float a0 = *(const float*)(wb + o0);
            float a1 = *(const float*)(wb + o1);
            float a2 = *(const float*)(wb + o2);
            float a3 = *(const float*)(wb + o3);
            float a4 = *(const float*)(wb + o4);
            float a5 = *(const float*)(wb + o5);
            float a6 = *(const float*)(wb + o6);
            float a7 = *(const float*)(wb + o7);
            R += ((a0 + a1) + (a2 + a3)) + ((a4 + a5) + (a6 + a7));
        }
        if (tid < F) o[(size_t)j * 3200] = W - R;   // pot at t = j
    }
}

// ---------- pool 2x2 s2 (min fire time) + pad=1 ----------
__global__ __launch_bounds__(256) void k_pool1(const unsigned char* __restrict__ ft1,
                                               unsigned char* __restrict__ ft1p) {
    int idx = blockIdx.x * 256 + threadIdx.x;
    const int total = NB * 90 * 17 * 17;
    if (idx >= total) return;
    int xx = idx % 17, rest = idx / 17;
    int yy = rest % 17; rest /= 17;
    int c = rest % 90;  int b = rest / 90;
    int ft = 15;
    if (xx >= 1 && xx < 16 && yy >= 1 && yy < 16) {
        const unsigned char* p = ft1 + ((size_t)b * 90 + c) * 900 + (yy - 1) * 2 * 30 + (xx - 1) * 2;
        int m = p[0];
        m = min(m, (int)p[1]);
        m = min(m, (int)p[30]);
        m = min(m, (int)p[31]);
        ft = m;
    }
    ft1p[idx] = (unsigned char)ft;
}

// ---------- pool 3x3 s3 (min fire time) + pad=2 ----------
__global__ __launch_bounds__(256) void k_pool2(const unsigned char* __restrict__ ft2,
                                               unsigned char* __restrict__ ft2p) {
    int idx = blockIdx.x * 256 + threadIdx.x;
    const int total = NB * 250 * 8 * 8;
    if (idx >= total) return;
    int xx = idx % 8, rest = idx / 8;
    int yy = rest % 8; rest /= 8;
    int c = rest % 250; int b = rest / 250;
    int ft = 15;
    if (xx >= 2 && xx < 6 && yy >= 2 && yy < 6) {
        const unsigned char* p = ft2 + ((size_t)b * 250 + c) * 169 + (yy - 2) * 3 * 13 + (xx - 2) * 3;
        int m = 15;
#pragma unroll
        for (int dy = 0; dy < 3; dy++)
#pragma unroll
            for (int dx = 0; dx < 3; dx++) m = min(m, (int)p[dy * 13 + dx]);
        ft = m;
    }
    ft2p[idx] = (unsigned char)ft;
}

// ---------- winner-take-all classification ----------
__global__ __launch_bounds__(256) void k_winner(const float* __restrict__ outp,
                                                float* __restrict__ outc) {
    int b = blockIdx.x, tid = threadIdx.x;
    const float* p14 = outp + 32 + ((size_t)b * NT + 14) * 3200;
    __shared__ float sv[256];
    __shared__ int   si[256];
    float m = 0.f;
    for (int j = tid; j < 3200; j += 256) {
        float v = p14[j];
        if (v > 0.f && v > m) m = v;
    }
    sv[tid] = m;
    __syncthreads();
    for (int s = 128; s > 0; s >>= 1) {
        if (tid < s) sv[tid] = fmaxf(sv[tid], sv[tid + s]);
        __syncthreads();
    }
    float vofs = 15.f * sv[0];
    __syncthreads();
    float bestv = 0.f; int besti = 0x3fffffff;
    for (int j = tid; j < 3200; j += 256) {
        float v = p14[j];
        float tot = (v > 0.f) ? v + vofs : 0.f;
        if (tot > bestv) { bestv = tot; besti = j; }
    }
    sv[tid] = bestv; si[tid] = besti;
    __syncthreads();
    for (int s = 128; s > 0; s >>= 1) {
        if (tid < s) {
            if (sv[tid + s] > sv[tid] || (sv[tid + s] == sv[tid] && si[tid + s] < si[tid])) {
                sv[tid] = sv[tid + s]; si[tid] = si[tid + s];
            }
        }
        __syncthreads();
    }
    if (tid == 0) {
        float mx = sv[0];
        int cls = (mx != 0.f) ? ((si[0] / 16) / 20) : -1;
        outc[b] = (float)cls;
    }
}

extern "C" void kernel_launch(void* const* d_in, const int* in_sizes, int n_in,
                              void* d_out, int out_size, void* d_ws, size_t ws_size,
                              hipStream_t stream) {
    const float* inp = (const float*)d_in[0];
    const float* w1  = (const float*)d_in[1];
    const float* w2  = (const float*)d_in[2];
    const float* w3  = (const float*)d_in[3];
    float* out = (float*)d_out;

    unsigned char* ws   = (unsigned char*)d_ws;
    unsigned char* ft0  = ws;
    unsigned char* ft1  = ws + 746496;
    unsigned char* ft1p = ws + 3338496;
    unsigned char* ft2  = ws + 4170816;
    unsigned char* ft2p = ws + 5522816;
    float* wT1 = (float*)(ws + 6034816);
    float* wT2 = (float*)(ws + 6352704);
    float* wT3 = (float*)(ws + 8603712);
    float* W2s = (float*)(ws + 13604544);
    float* W3s = (float*)(ws + 13605568);

    hipLaunchKernelGGL(k_zero, dim3(14), dim3(256), 0, stream, W2s);
    hipLaunchKernelGGL(k_ft0, dim3((NB * 18 * 36 * 36 + 255) / 256), dim3(256), 0, stream, inp, ft0);
    hipLaunchKernelGGL((k_tr<90, 882>),    dim3((883 * 90 + 255) / 256),    dim3(256), 0, stream, w1, wT1);
    hipLaunchKernelGGL((k_tr<250, 2250>),  dim3((2251 * 250 + 255) / 256),  dim3(256), 0, stream, w2, wT2);
    hipLaunchKernelGGL((k_tr<200, 6250>),  dim3((6251 * 200 + 255) / 256),  dim3(256), 0, stream, w3, wT3);
    hipLaunchKernelGGL(k_colsum2, dim3(15), dim3(256), 0, stream, wT2, W2s);
    hipLaunchKernelGGL(k_w3s, dim3(16, 10), dim3(256), 0, stream, wT3, W3s);

    hipLaunchKernelGGL((k_conv_sorted<882, 90, 128, 7, 30, 900, 36, 1296, 18>),
                       dim3(900, NB), dim3(128), 0, stream, ft0, wT1, ft1, 15.0f);
    hipLaunchKernelGGL(k_pool1, dim3((NB * 90 * 289 + 255) / 256), dim3(256), 0, stream, ft1, ft1p);
    hipLaunchKernelGGL(k_conv2c, dim3(169, NB), dim3(256), 0, stream, ft1p, wT2, W2s, ft2);
    hipLaunchKernelGGL(k_pool2, dim3((NB * 250 * 64 + 255) / 256), dim3(256), 0, stream, ft2, ft2p);
    hipLaunchKernelGGL(k_conv3c, dim3(16, NB), dim3(256), 0, stream, ft2p, wT3, W3s, out);
    hipLaunchKernelGGL(k_winner, dim3(NB), dim3(256), 0, stream, out, out);
}

// Round 6
// 296.536 us; speedup vs baseline: 20.7031x; 1.2408x over previous
//
#include <hip/hip_runtime.h>

#define NB 32
#define NT 15

// Workspace layout (byte offsets):
//  ft0  : 0        (B,18,36,36) u8 input fire times, pad=2      746496
//  ft1  : 746496   (B,90,30,30) u8 layer-1 fire times          2592000
//  ft1p : 3338496  (B,90,17,17) u8 pool2x2s2 + pad=1            832320
//  ft2  : 4170816  (B,250,13,13) u8 layer-2 fire times         1352000
//  ft2p : 5522816  (B,250,8,8)  u8 pool3x3s3 + pad=2            512000
//  wT1  : 6034816  (883,90) f32 w1^T + zero row                 317888
//  wT2  : 6352704  (2251,250) f32 w2^T + zero row              2251008
//  wT3  : 8603712  (6251,200) f32 w3^T + zero row              5000832
//  W2s  : 13604544 (256) f32 col sums of wT2                      1024
//  W3s  : 13605568 (16,200) f32 per-px valid-tap col sums of wT3 12800

// ---------- zero the weight-sum buffers (3456 floats) ----------
__global__ __launch_bounds__(256) void k_zero(float* __restrict__ p) {
    int idx = blockIdx.x * 256 + threadIdx.x;
    if (idx < 3456) p[idx] = 0.f;
}

// ---------- K0: input fire times (padded plane) ----------
__global__ __launch_bounds__(256) void k_ft0(const float* __restrict__ inp,
                                             unsigned char* __restrict__ ft0) {
    int idx = blockIdx.x * 256 + threadIdx.x;
    const int total = NB * 18 * 36 * 36;
    if (idx >= total) return;
    int xx = idx % 36, rest = idx / 36;
    int yy = rest % 36; rest /= 36;
    int c = rest % 18;  int b = rest / 18;
    int ft = 15;
    int x = xx - 2, y = yy - 2;
    if (x >= 0 && x < 32 && y >= 0 && y < 32) {
        int cnt = 0;
        const float* p = inp + ((size_t)(b * NT) * 18 + c) * 1024 + y * 32 + x;
#pragma unroll
        for (int t = 0; t < NT; t++) cnt += (p[(size_t)t * 18 * 1024] != 0.f);
        ft = 15 - cnt;   // cumulative wave: #ones == 15 - fire_time
    }
    ft0[idx] = (unsigned char)ft;
}

// ---------- weight transpose (OIHW -> [tap][f]) with zero pad row ----------
template<int F, int K>
__global__ __launch_bounds__(256) void k_tr(const float* __restrict__ src,
                                            float* __restrict__ dst) {
    int idx = blockIdx.x * 256 + threadIdx.x;
    const int total = (K + 1) * F;
    if (idx >= total) return;
    int k = idx / F, f = idx - k * F;
    dst[idx] = (k < K) ? src[f * K + k] : 0.f;
}

// ---------- column sums of wT2 -> W2s[250] (45 blocks x 50 rows) ----------
__global__ __launch_bounds__(256) void k_colsum2(const float* __restrict__ wT2,
                                                 float* __restrict__ W2s) {
    int tid = threadIdx.x;
    int f = tid < 250 ? tid : 249;
    int k0 = blockIdx.x * 50;
    float acc = 0.f;
    for (int k = k0; k < k0 + 50; k++) acc += wT2[(size_t)k * 250 + f];
    if (tid < 250) atomicAdd(&W2s[tid], acc);
}

// ---------- per-px valid-tap column sums of wT3 (16 px x 50 chunks of 5 ch) ----------
__global__ __launch_bounds__(256) void k_w3s(const float* __restrict__ wT3,
                                             float* __restrict__ W3s) {
    int tid = threadIdx.x;
    int f = tid < 200 ? tid : 199;
    int px = blockIdx.x, ch = blockIdx.y;
    int oy = px >> 2, ox = px & 3;
    int r0 = max(0, 2 - oy), r1 = min(4, 5 - oy);
    int x0 = max(0, 2 - ox), x1 = min(4, 5 - ox);
    float acc = 0.f;
    for (int c = ch * 5; c < ch * 5 + 5; c++)
        for (int r = r0; r <= r1; r++)
            for (int x = x0; x <= x1; x++)
                acc += wT3[(size_t)(c * 25 + r * 5 + x) * 200 + f];
    if (tid < 200) atomicAdd(&W3s[px * 200 + tid], acc);
}

// ---------- sorted-prefix conv1 (fire-time output), early-exit ----------
template<int TAPS, int F, int BLOCK, int KW, int OW, int NPX, int IH, int IPLANE, int CIN>
__global__ __launch_bounds__(BLOCK) void k_conv_sorted(const unsigned char* __restrict__ ftin,
                                                       const float* __restrict__ wT,
                                                       unsigned char* __restrict__ ftout,
                                                       float thr) {
    constexpr int PADCAP = TAPS + 15 * 8;
    __shared__ unsigned char ftl[TAPS];
    __shared__ __align__(16) int perm[PADCAP];
    __shared__ int start[16];
    __shared__ int cur[16];
    int tid = threadIdx.x;
    int px = blockIdx.x, b = blockIdx.y;
    int oy = px / OW, ox = px - oy * OW;
    const unsigned char* base = ftin + (size_t)b * CIN * IPLANE + oy * IH + ox;

    for (int i = tid; i < TAPS; i += BLOCK) {
        int c = i / (KW * KW); int rem = i - c * (KW * KW);
        int r = rem / KW; int x = rem - r * KW;
        ftl[i] = base[c * IPLANE + r * IH + x];
    }
    if (tid < 16) cur[tid] = 0;
    __syncthreads();
    for (int i = tid; i < TAPS; i += BLOCK) {
        int v = ftl[i];
        if (v < 15) atomicAdd(&cur[v], 1);
    }
    __syncthreads();
    if (tid == 0) {
        int s = 0;
#pragma unroll
        for (int j = 0; j < 15; j++) { int c = cur[j]; start[j] = s; s += (c + 7) & ~7; }
        start[15] = s;
    }
    __syncthreads();
    int nnzp = start[15];
    if (tid < 15) cur[tid] = start[tid];
    const int zoff = TAPS * F * 4;
    for (int i = tid; i < nnzp; i += BLOCK) perm[i] = zoff;
    __syncthreads();
    for (int i = tid; i < TAPS; i += BLOCK) {
        int v = ftl[i];
        if (v < 15) { int p = atomicAdd(&cur[v], 1); perm[p] = i * (F * 4); }
    }
    __syncthreads();

    int f = tid < F ? tid : F - 1;
    const char* wb = (const char*)(wT + f);
    float acc = 0.f; int ft = 15;
    for (int s = 0; s < 15; s++) {
        int e = start[s + 1];
        for (int i = start[s]; i < e; i += 8) {
            int4 p0 = *(const int4*)(perm + i);
            int4 p1 = *(const int4*)(perm + i + 4);
            int o0 = __builtin_amdgcn_readfirstlane(p0.x);
            int o1 = __builtin_amdgcn_readfirstlane(p0.y);
            int o2 = __builtin_amdgcn_readfirstlane(p0.z);
            int o3 = __builtin_amdgcn_readfirstlane(p0.w);
            int o4 = __builtin_amdgcn_readfirstlane(p1.x);
            int o5 = __builtin_amdgcn_readfirstlane(p1.y);
            int o6 = __builtin_amdgcn_readfirstlane(p1.z);
            int o7 = __builtin_amdgcn_readfirstlane(p1.w);
            float a0 = *(const float*)(wb + o0);
            float a1 = *(const float*)(wb + o1);
            float a2 = *(const float*)(wb + o2);
            float a3 = *(const float*)(wb + o3);
            float a4 = *(const float*)(wb + o4);
            float a5 = *(const float*)(wb + o5);
            float a6 = *(const float*)(wb + o6);
            float a7 = *(const float*)(wb + o7);
            acc += ((a0 + a1) + (a2 + a3)) + ((a4 + a5) + (a6 + a7));
        }
        if (ft == 15 && acc > thr) ft = s;
        if (__all(ft != 15)) break;
    }
    if (tid < F) ftout[((size_t)b * F + tid) * NPX + px] = (unsigned char)ft;
}

// ---------- conv2 complement walk: pot_t = W_f - sum_{ft>t} w ----------
__global__ __launch_bounds__(256) void k_conv2c(const unsigned char* __restrict__ ft1p,
                                                const float* __restrict__ wT2,
                                                const float* __restrict__ W2s,
                                                unsigned char* __restrict__ ft2) {
    constexpr int TAPS = 2250, F = 250, BLOCK = 256;
    constexpr int PADCAP = TAPS + 15 * 8;
    __shared__ unsigned char ftl[TAPS];
    __shared__ __align__(16) int perm[PADCAP];
    __shared__ int start[16];
    __shared__ int cur[16];
    int tid = threadIdx.x;
    int px = blockIdx.x, b = blockIdx.y;
    int oy = px / 13, ox = px - oy * 13;
    const unsigned char* base = ft1p + (size_t)b * 90 * 289 + oy * 17 + ox;

    for (int i = tid; i < TAPS; i += BLOCK) {
        int c = i / 25; int rem = i - c * 25;
        int r = rem / 5; int x = rem - r * 5;
        ftl[i] = base[c * 289 + r * 17 + x];
    }
    if (tid < 16) cur[tid] = 0;
    __syncthreads();
    for (int i = tid; i < TAPS; i += BLOCK) {
        int v = ftl[i];
        if (v >= 1) atomicAdd(&cur[v - 1], 1);
    }
    __syncthreads();
    if (tid == 0) {
        int s = 0;
#pragma unroll
        for (int j = 0; j < 15; j++) { int c = cur[j]; start[j] = s; s += (c + 7) & ~7; }
        start[15] = s;
    }
    __syncthreads();
    int nnzp = start[15];
    if (tid < 15) cur[tid] = start[tid];
    const int zoff = TAPS * F * 4;
    for (int i = tid; i < nnzp; i += BLOCK) perm[i] = zoff;
    __syncthreads();
    for (int i = tid; i < TAPS; i += BLOCK) {
        int v = ftl[i];
        if (v >= 1) { int p = atomicAdd(&cur[v - 1], 1); perm[p] = i * (F * 4); }
    }
    __syncthreads();

    int f = tid < F ? tid : F - 1;
    const char* wb = (const char*)(wT2 + f);
    float W = W2s[f];
    float R = 0.f; int ft = 15;
    for (int j = 14; j >= 0; j--) {
        int e = start[j + 1];
        for (int i = start[j]; i < e; i += 8) {
            int4 p0 = *(const int4*)(perm + i);
            int4 p1 = *(const int4*)(perm + i + 4);
            int o0 = __builtin_amdgcn_readfirstlane(p0.x);
            int o1 = __builtin_amdgcn_readfirstlane(p0.y);
            int o2 = __builtin_amdgcn_readfirstlane(p0.z);
            int o3 = __builtin_amdgcn_readfirstlane(p0.w);
            int o4 = __builtin_amdgcn_readfirstlane(p1.x);
            int o5 = __builtin_amdgcn_readfirstlane(p1.y);
            int o6 = __builtin_amdgcn_readfirstlane(p1.z);
            int o7 = __builtin_amdgcn_readfirstlane(p1.w);
            float a0 = *(const float*)(wb + o0);
            float a1 = *(const float*)(wb + o1);
            float a2 = *(const float*)(wb + o2);
            float a3 = *(const float*)(wb + o3);
            float a4 = *(const float*)(wb + o4);
            float a5 = *(const float*)(wb + o5);
            float a6 = *(const float*)(wb + o6);
            float a7 = *(const float*)(wb + o7);
            R += ((a0 + a1) + (a2 + a3)) + ((a4 + a5) + (a6 + a7));
        }
        float pot = W - R;
        if (pot > 10.0f) ft = j;
        else if (__all(pot <= 10.0f)) break;
    }
    if (tid < F) ft2[((size_t)b * F + tid) * 169 + px] = (unsigned char)ft;
}

// ---------- conv3 complement walk over VALID taps; stores all 15 pots ----------
__global__ __launch_bounds__(256) void k_conv3c(const unsigned char* __restrict__ ft2p,
                                                const float* __restrict__ wT3,
                                                const float* __restrict__ W3s,
                                                float* __restrict__ out) {
    constexpr int F = 200, BLOCK = 256, MAXV = 4000;
    constexpr int PADCAP = MAXV + 15 * 8;
    __shared__ unsigned char ftl[MAXV];
    __shared__ __align__(16) int perm[PADCAP];
    __shared__ int start[16];
    __shared__ int cur[16];
    int tid = threadIdx.x;
    int px = blockIdx.x, b = blockIdx.y;
    int oy = px >> 2, ox = px & 3;
    int r0 = max(0, 2 - oy), r1 = min(4, 5 - oy);
    int x0 = max(0, 2 - ox), x1 = min(4, 5 - ox);
    int VR = r1 - r0 + 1, VC = x1 - x0 + 1;
    int NV = 250 * VR * VC;
    const unsigned char* base = ft2p + (size_t)b * 250 * 64;

    for (int i = tid; i < NV; i += BLOCK) {
        int c = i / (VR * VC); int rem = i - c * (VR * VC);
        int r = r0 + rem / VC; int x = x0 + rem % VC;
        ftl[i] = base[c * 64 + (oy + r) * 8 + (ox + x)];
        perm[i] = (c * 25 + r * 5 + x) * (F * 4);
    }
    if (tid < 16) cur[tid] = 0;
    __syncthreads();
    for (int i = tid; i < NV; i += BLOCK) {
        int v = ftl[i];
        if (v >= 1) atomicAdd(&cur[v - 1], 1);
    }
    __syncthreads();
    __shared__ int rowoff[MAXV];
    for (int i = tid; i < NV; i += BLOCK) rowoff[i] = perm[i];
    __syncthreads();
    if (tid == 0) {
        int s = 0;
#pragma unroll
        for (int j = 0; j < 15; j++) { int c = cur[j]; start[j] = s; s += (c + 7) & ~7; }
        start[15] = s;
    }
    __syncthreads();
    int nnzp = start[15];
    if (tid < 15) cur[tid] = start[tid];
    const int zoff = 6250 * F * 4;
    for (int i = tid; i < nnzp; i += BLOCK) perm[i] = zoff;
    __syncthreads();
    for (int i = tid; i < NV; i += BLOCK) {
        int v = ftl[i];
        if (v >= 1) { int p = atomicAdd(&cur[v - 1], 1); perm[p] = rowoff[i]; }
    }
    __syncthreads();

    int f = tid < F ? tid : F - 1;
    const char* wb = (const char*)(wT3 + f);
    float W = W3s[px * F + f];
    float* o = out + 32 + ((size_t)b * NT) * 3200 + f * 16 + px;
    float R = 0.f;
    for (int j = 14; j >= 0; j--) {
        int e = start[j + 1];
        for (int i = start[j]; i < e; i += 8) {
            int4 p0 = *(const int4*)(perm + i);
            int4 p1 = *(const int4*)(perm + i + 4);
            int o0 = __builtin_amdgcn_readfirstlane(p0.x);
            int o1 = __builtin_amdgcn_readfirstlane(p0.y);
            int o2 = __builtin_amdgcn_readfirstlane(p0.z);
            int o3 = __builtin_amdgcn_readfirstlane(p0.w);
            int o4 = __builtin_amdgcn_readfirstlane(p1.x);
            int o5 = __builtin_amdgcn_readfirstlane(p1.y);
            int o6 = __builtin_amdgcn_readfirstlane(p1.z);
            int o7 = __builtin_amdgcn_readfirstlane(p1.w);
            float a0 = *(const float*)(wb + o0);
            float a1 = *(const float*)(wb + o1);
            float a2 = *(const float*)(wb + o2);
            float a3 = *(const float*)(wb + o3);
            float a4 = *(const float*)(wb + o4);
            float a5 = *(const float*)(wb + o5);
            float a6 = *(const float*)(wb + o6);
            float a7 = *(const float*)(wb + o7);
            R += ((a0 + a1) + (a2 + a3)) + ((a4 + a5) + (a6 + a7));
        }
        if (tid < F) o[(size_t)j * 3200] = W - R;
    }
}

// ---------- pool 2x2 s2 (min fire time) + pad=1 ----------
__global__ __launch_bounds__(256) void k_pool1(const unsigned char* __restrict__ ft1,
                                               unsigned char* __restrict__ ft1p) {
    int idx = blockIdx.x * 256 + threadIdx.x;
    const int total = NB * 90 * 17 * 17;
    if (idx >= total) return;
    int xx = idx % 17, rest = idx / 17;
    int yy = rest % 17; rest /= 17;
    int c = rest % 90;  int b = rest / 90;
    int ft = 15;
    if (xx >= 1 && xx < 16 && yy >= 1 && yy < 16) {
        const unsigned char* p = ft1 + ((size_t)b * 90 + c) * 900 + (yy - 1) * 2 * 30 + (xx - 1) * 2;
        int m = p[0];
        m = min(m, (int)p[1]);
        m = min(m, (int)p[30]);
        m = min(m, (int)p[31]);
        ft = m;
    }
    ft1p[idx] = (unsigned char)ft;
}

// ---------- pool 3x3 s3 (min fire time) + pad=2 ----------
__global__ __launch_bounds__(256) void k_pool2(const unsigned char* __restrict__ ft2,
                                               unsigned char* __restrict__ ft2p) {
    int idx = blockIdx.x * 256 + threadIdx.x;
    const int total = NB * 250 * 8 * 8;
    if (idx >= total) return;
    int xx = idx % 8, rest = idx / 8;
    int yy = rest % 8; rest /= 8;
    int c = rest % 250; int b = rest / 250;
    int ft = 15;
    if (xx >= 2 && xx < 6 && yy >= 2 && yy < 6) {
        const unsigned char* p = ft2 + ((size_t)b * 250 + c) * 169 + (yy - 2) * 3 * 13 + (xx - 2) * 3;
        int m = 15;
#pragma unroll
        for (int dy = 0; dy < 3; dy++)
#pragma unroll
            for (int dx = 0; dx < 3; dx++) m = min(m, (int)p[dy * 13 + dx]);
        ft = m;
    }
    ft2p[idx] = (unsigned char)ft;
}

// ---------- winner-take-all classification ----------
__global__ __launch_bounds__(256) void k_winner(const float* __restrict__ outp,
                                                float* __restrict__ outc) {
    int b = blockIdx.x, tid = threadIdx.x;
    const float* p14 = outp + 32 + ((size_t)b * NT + 14) * 3200;
    __shared__ float sv[256];
    __shared__ int   si[256];
    float m = 0.f;
    for (int j = tid; j < 3200; j += 256) {
        float v = p14[j];
        if (v > 0.f && v > m) m = v;
    }
    sv[tid] = m;
    __syncthreads();
    for (int s = 128; s > 0; s >>= 1) {
        if (tid < s) sv[tid] = fmaxf(sv[tid], sv[tid + s]);
        __syncthreads();
    }
    float vofs = 15.f * sv[0];
    __syncthreads();
    float bestv = 0.f; int besti = 0x3fffffff;
    for (int j = tid; j < 3200; j += 256) {
        float v = p14[j];
        float tot = (v > 0.f) ? v + vofs : 0.f;
        if (tot > bestv) { bestv = tot; besti = j; }
    }
    sv[tid] = bestv; si[tid] = besti;
    __syncthreads();
    for (int s = 128; s > 0; s >>= 1) {
        if (tid < s) {
            if (sv[tid + s] > sv[tid] || (sv[tid + s] == sv[tid] && si[tid + s] < si[tid])) {
                sv[tid] = sv[tid + s]; si[tid] = si[tid + s];
            }
        }
        __syncthreads();
    }
    if (tid == 0) {
        float mx = sv[0];
        int cls = (mx != 0.f) ? ((si[0] / 16) / 20) : -1;
        outc[b] = (float)cls;
    }
}

extern "C" void kernel_launch(void* const* d_in, const int* in_sizes, int n_in,
                              void* d_out, int out_size, void* d_ws, size_t ws_size,
                              hipStream_t stream) {
    const float* inp = (const float*)d_in[0];
    const float* w1  = (const float*)d_in[1];
    const float* w2  = (const float*)d_in[2];
    const float* w3  = (const float*)d_in[3];
    float* out = (float*)d_out;

    unsigned char* ws   = (unsigned char*)d_ws;
    unsigned char* ft0  = ws;
    unsigned char* ft1  = ws + 746496;
    unsigned char* ft1p = ws + 3338496;
    unsigned char* ft2  = ws + 4170816;
    unsigned char* ft2p = ws + 5522816;
    float* wT1 = (float*)(ws + 6034816);
    float* wT2 = (float*)(ws + 6352704);
    float* wT3 = (float*)(ws + 8603712);
    float* W2s = (float*)(ws + 13604544);
    float* W3s = (float*)(ws + 13605568);

    hipLaunchKernelGGL(k_zero, dim3(14), dim3(256), 0, stream, W2s);
    hipLaunchKernelGGL(k_ft0, dim3((NB * 18 * 36 * 36 + 255) / 256), dim3(256), 0, stream, inp, ft0);
    hipLaunchKernelGGL((k_tr<90, 882>),    dim3((883 * 90 + 255) / 256),    dim3(256), 0, stream, w1, wT1);
    hipLaunchKernelGGL((k_tr<250, 2250>),  dim3((2251 * 250 + 255) / 256),  dim3(256), 0, stream, w2, wT2);
    hipLaunchKernelGGL((k_tr<200, 6250>),  dim3((6251 * 200 + 255) / 256),  dim3(256), 0, stream, w3, wT3);
    hipLaunchKernelGGL(k_colsum2, dim3(45), dim3(256), 0, stream, wT2, W2s);
    hipLaunchKernelGGL(k_w3s, dim3(16, 50), dim3(256), 0, stream, wT3, W3s);

    hipLaunchKernelGGL((k_conv_sorted<882, 90, 128, 7, 30, 900, 36, 1296, 18>),
                       dim3(900, NB), dim3(128), 0, stream, ft0, wT1, ft1, 15.0f);
    hipLaunchKernelGGL(k_pool1, dim3((NB * 90 * 289 + 255) / 256), dim3(256), 0, stream, ft1, ft1p);
    hipLaunchKernelGGL(k_conv2c, dim3(169, NB), dim3(256), 0, stream, ft1p, wT2, W2s, ft2);
    hipLaunchKernelGGL(k_pool2, dim3((NB * 250 * 64 + 255) / 256), dim3(256), 0, stream, ft2, ft2p);
    hipLaunchKernelGGL(k_conv3c, dim3(16, NB), dim3(256), 0, stream, ft2p, wT3, W3s, out);
    hipLaunchKernelGGL(k_winner, dim3(NB), dim3(256), 0, stream, out, out);
}

// Round 7
// 275.480 us; speedup vs baseline: 22.2856x; 1.0764x over previous
//
#include <hip/hip_runtime.h>

#define NB 32
#define NT 15

// Workspace layout (byte offsets) — channel-last fire-time maps:
//  ft0  : 0        (B,36,36,18) u8 input fire times, pad=2 ring  746496
//  ft1  : 746496   (B,90,30,30) u8 layer-1 fire times           2592000
//  ft1p : 3338496  (B,17,17,90) u8 pool2x2s2 + pad=1             832320
//  ft2  : 4170816  (B,250,13,13) u8 layer-2 fire times          1352000
//  ft2p : 5522816  (B,8,8,250)  u8 pool3x3s3 + pad=2             512000
//  wT1  : 6034816  (883,90)  f32 w1^T rows j=(r*7+x)*18+c  + 0   317888
//  wT2  : 6352704  (2251,250) f32 w2^T rows j=(r*5+x)*90+c + 0  2251008
//  wT3  : 8603712  (6251,200) f32 w3^T rows j=(r*5+x)*250+c + 0 5000832
//  W2s  : 13604544 (256) f32 col sums of wT2                       1024
//  W3s  : 13605568 (16,200) f32 per-px valid-tap col sums          12800

// ---------- zero weight-sum buffers (3456 floats) ----------
__global__ __launch_bounds__(256) void k_zero(float* __restrict__ p) {
    int idx = blockIdx.x * 256 + threadIdx.x;
    if (idx < 3456) p[idx] = 0.f;
}

// ---------- input fire times, channel-last; thread = (b,yy,xx,group-of-3ch) ----------
__global__ __launch_bounds__(256) void k_ft0c(const float* __restrict__ inp,
                                              unsigned char* __restrict__ ft0) {
    int idx = blockIdx.x * 256 + threadIdx.x;
    if (idx >= NB * 36 * 36 * 6) return;
    int g = idx % 6, rest = idx / 6;
    int xx = rest % 36; rest /= 36;
    int yy = rest % 36; int b = rest / 36;
    unsigned char* dst = ft0 + ((size_t)(b * 36 + yy) * 36 + xx) * 18 + g * 3;
    int x = xx - 2, y = yy - 2;
    if (x >= 0 && x < 32 && y >= 0 && y < 32) {
        int c0 = 0, c1 = 0, c2 = 0;
        const float* p = inp + ((size_t)b * NT * 18 + g * 3) * 1024 + y * 32 + x;
#pragma unroll
        for (int t = 0; t < NT; t++) {
            c0 += (p[(size_t)(t * 18 + 0) * 1024] != 0.f);
            c1 += (p[(size_t)(t * 18 + 1) * 1024] != 0.f);
            c2 += (p[(size_t)(t * 18 + 2) * 1024] != 0.f);
        }
        dst[0] = (unsigned char)(15 - c0);
        dst[1] = (unsigned char)(15 - c1);
        dst[2] = (unsigned char)(15 - c2);
    } else {
        dst[0] = 15; dst[1] = 15; dst[2] = 15;
    }
}

// ---------- weight transpose: dst[j][f], j=(r*KW+x)*CIN+c, + zero row ----------
template<int F, int CIN, int KW>
__global__ __launch_bounds__(256) void k_tr(const float* __restrict__ src,
                                            float* __restrict__ dst) {
    constexpr int K = CIN * KW * KW;
    int idx = blockIdx.x * 256 + threadIdx.x;
    if (idx >= (K + 1) * F) return;
    int j = idx / F, f = idx - j * F;
    float v = 0.f;
    if (j < K) {
        int c = j % CIN, pos = j / CIN;
        v = src[(size_t)f * K + c * (KW * KW) + pos];
    }
    dst[idx] = v;
}

// ---------- column sums of wT2 -> W2s[250] ----------
__global__ __launch_bounds__(256) void k_colsum2(const float* __restrict__ wT2,
                                                 float* __restrict__ W2s) {
    int tid = threadIdx.x;
    int f = tid < 250 ? tid : 249;
    int k0 = blockIdx.x * 50;
    float acc = 0.f;
    for (int k = k0; k < k0 + 50; k++) acc += wT2[(size_t)k * 250 + f];
    if (tid < 250) atomicAdd(&W2s[tid], acc);
}

// ---------- per-px valid-tap column sums of wT3 ----------
__global__ __launch_bounds__(256) void k_w3s(const float* __restrict__ wT3,
                                             float* __restrict__ W3s) {
    int tid = threadIdx.x;
    int f = tid < 200 ? tid : 199;
    int px = blockIdx.x, ch = blockIdx.y;
    int oy = px >> 2, ox = px & 3;
    int r0 = max(0, 2 - oy), r1 = min(4, 5 - oy);
    int x0 = max(0, 2 - ox), x1 = min(4, 5 - ox);
    float acc = 0.f;
    for (int c = ch * 5; c < ch * 5 + 5; c++)
        for (int r = r0; r <= r1; r++)
            for (int x = x0; x <= x1; x++)
                acc += wT3[(size_t)((r * 5 + x) * 250 + c) * 200 + f];
    if (tid < 200) atomicAdd(&W3s[px * 200 + tid], acc);
}

// ---------- conv1: lazy per-bucket compaction, register taps, block-wide exit ----------
__global__ __launch_bounds__(128) void k_conv1f(const unsigned char* __restrict__ ft0,
                                                const float* __restrict__ wT1,
                                                unsigned char* __restrict__ ft1) {
    __shared__ __align__(16) int list[896];
    __shared__ int cnt, pcnt;
    int tid = threadIdx.x;
    int px = blockIdx.x, b = blockIdx.y;
    int oy = px / 30, ox = px - oy * 30;
    const unsigned char* base = ft0 + ((size_t)(b * 36 + oy) * 36 + ox) * 18;
    unsigned char myft[7];
#pragma unroll
    for (int k = 0; k < 7; k++) {
        int j = tid + k * 128;
        if (j < 882) {
            int c = j % 18, pos = j / 18;
            int r = pos / 7, x = pos - r * 7;
            myft[k] = base[(r * 36 + x) * 18 + c];
        } else myft[k] = 255;
    }
    int f = tid < 90 ? tid : 89;
    const char* wb = (const char*)(wT1 + f);
    const int zoff = 882 * 90 * 4;
    float acc = 0.f; int ft = 15;
    for (int s = 0; s < 15; s++) {
        if (tid == 0) cnt = 0;
        __syncthreads();
#pragma unroll
        for (int k = 0; k < 7; k++) {
            if ((int)myft[k] == s) { int p = atomicAdd(&cnt, 1); list[p] = (tid + k * 128) * 360; }
        }
        __syncthreads();
        if (tid == 0) {
            int c0 = cnt, cp = (c0 + 7) & ~7;
            for (int i = c0; i < cp; i++) list[i] = zoff;
            pcnt = cp;
        }
        __syncthreads();
        int e = pcnt;
        for (int i = 0; i < e; i += 8) {
            int4 p0 = *(const int4*)(list + i);
            int4 p1 = *(const int4*)(list + i + 4);
            int o0 = __builtin_amdgcn_readfirstlane(p0.x);
            int o1 = __builtin_amdgcn_readfirstlane(p0.y);
            int o2 = __builtin_amdgcn_readfirstlane(p0.z);
            int o3 = __builtin_amdgcn_readfirstlane(p0.w);
            int o4 = __builtin_amdgcn_readfirstlane(p1.x);
            int o5 = __builtin_amdgcn_readfirstlane(p1.y);
            int o6 = __builtin_amdgcn_readfirstlane(p1.z);
            int o7 = __builtin_amdgcn_readfirstlane(p1.w);
            float a0 = *(const float*)(wb + o0);
            float a1 = *(const float*)(wb + o1);
            float a2 = *(const float*)(wb + o2);
            float a3 = *(const float*)(wb + o3);
            float a4 = *(const float*)(wb + o4);
            float a5 = *(const float*)(wb + o5);
            float a6 = *(const float*)(wb + o6);
            float a7 = *(const float*)(wb + o7);
            acc += ((a0 + a1) + (a2 + a3)) + ((a4 + a5) + (a6 + a7));
        }
        if (ft == 15 && acc > 15.0f) ft = s;
        if (__syncthreads_and(ft != 15)) break;
    }
    if (tid < 90) ft1[((size_t)b * 90 + tid) * 900 + px] = (unsigned char)ft;
}

// ---------- conv2 complement walk, register taps, coalesced staging ----------
__global__ __launch_bounds__(256) void k_conv2cr(const unsigned char* __restrict__ ft1p,
                                                 const float* __restrict__ wT2,
                                                 const float* __restrict__ W2s,
                                                 unsigned char* __restrict__ ft2) {
    constexpr int PADCAP = 2250 + 15 * 8;
    __shared__ __align__(16) int perm[PADCAP];
    __shared__ int start[16], cur[16];
    int tid = threadIdx.x;
    int px = blockIdx.x, b = blockIdx.y;
    int oy = px / 13, ox = px - oy * 13;
    const unsigned char* base = ft1p + ((size_t)(b * 17 + oy) * 17 + ox) * 90;
    unsigned char myft[9];
#pragma unroll
    for (int k = 0; k < 9; k++) {
        int j = tid + k * 256;
        if (j < 2250) {
            int c = j % 90, pos = j / 90;
            int r = pos / 5, x = pos - r * 5;
            myft[k] = base[(r * 17 + x) * 90 + c];
        } else myft[k] = 0;   // ft=0 -> not in complement
    }
    if (tid < 16) cur[tid] = 0;
    __syncthreads();
#pragma unroll
    for (int k = 0; k < 9; k++) { int v = myft[k]; if (v >= 1) atomicAdd(&cur[v - 1], 1); }
    __syncthreads();
    if (tid == 0) {
        int s = 0;
#pragma unroll
        for (int j = 0; j < 15; j++) { int c = cur[j]; start[j] = s; s += (c + 7) & ~7; }
        start[15] = s;
    }
    __syncthreads();
    int nnzp = start[15];
    if (tid < 15) cur[tid] = start[tid];
    const int zoff = 2250 * 250 * 4;
    for (int i = tid; i < nnzp; i += 256) perm[i] = zoff;
    __syncthreads();
#pragma unroll
    for (int k = 0; k < 9; k++) {
        int v = myft[k];
        if (v >= 1) { int p = atomicAdd(&cur[v - 1], 1); perm[p] = (tid + k * 256) * 1000; }
    }
    __syncthreads();

    int f = tid < 250 ? tid : 249;
    const char* wb = (const char*)(wT2 + f);
    float W = W2s[f];
    float R = 0.f; int ft = 15;
    for (int j = 14; j >= 0; j--) {
        int e = start[j + 1];
        for (int i = start[j]; i < e; i += 8) {
            int4 p0 = *(const int4*)(perm + i);
            int4 p1 = *(const int4*)(perm + i + 4);
            int o0 = __builtin_amdgcn_readfirstlane(p0.x);
            int o1 = __builtin_amdgcn_readfirstlane(p0.y);
            int o2 = __builtin_amdgcn_readfirstlane(p0.z);
            int o3 = __builtin_amdgcn_readfirstlane(p0.w);
            int o4 = __builtin_amdgcn_readfirstlane(p1.x);
            int o5 = __builtin_amdgcn_readfirstlane(p1.y);
            int o6 = __builtin_amdgcn_readfirstlane(p1.z);
            int o7 = __builtin_amdgcn_readfirstlane(p1.w);
            float a0 = *(const float*)(wb + o0);
            float a1 = *(const float*)(wb + o1);
            float a2 = *(const float*)(wb + o2);
            float a3 = *(const float*)(wb + o3);
            float a4 = *(const float*)(wb + o4);
            float a5 = *(const float*)(wb + o5);
            float a6 = *(const float*)(wb + o6);
            float a7 = *(const float*)(wb + o7);
            R += ((a0 + a1) + (a2 + a3)) + ((a4 + a5) + (a6 + a7));
        }
        float pot = W - R;
        if (pot > 10.0f) ft = j;
        else if (__all(pot <= 10.0f)) break;
    }
    if (tid < 250) ft2[((size_t)b * 250 + tid) * 169 + px] = (unsigned char)ft;
}

// ---------- conv3 complement walk over VALID taps; stores all 15 pots ----------
__global__ __launch_bounds__(256) void k_conv3cr(const unsigned char* __restrict__ ft2p,
                                                 const float* __restrict__ wT3,
                                                 const float* __restrict__ W3s,
                                                 float* __restrict__ out) {
    constexpr int PADCAP = 4000 + 15 * 8;
    __shared__ __align__(16) int perm[PADCAP];
    __shared__ int start[16], cur[16];
    __shared__ int offs[16], rowb[16];
    int tid = threadIdx.x;
    int px = blockIdx.x, b = blockIdx.y;
    int oy = px >> 2, ox = px & 3;
    int r0 = max(0, 2 - oy), r1 = min(4, 5 - oy);
    int x0 = max(0, 2 - ox), x1 = min(4, 5 - ox);
    int VR = r1 - r0 + 1, VC = x1 - x0 + 1;
    int NP = VR * VC, NV = NP * 250;
    if (tid < NP) {
        int rv = tid / VC, xv = tid - rv * VC;
        offs[tid] = ((r0 + rv) * 8 + (x0 + xv)) * 250;
        rowb[tid] = ((r0 + rv) * 5 + (x0 + xv)) * 250;
    }
    if (tid < 16) cur[tid] = 0;
    const unsigned char* base = ft2p + ((size_t)(b * 8 + oy) * 8 + ox) * 250;
    __syncthreads();
    unsigned char myft[16];
#pragma unroll
    for (int k = 0; k < 16; k++) {
        int i = tid + k * 256;
        myft[k] = 0;
        if (i < NV) {
            int posv = i / 250, c = i - posv * 250;
            myft[k] = base[offs[posv] + c];
        }
    }
#pragma unroll
    for (int k = 0; k < 16; k++) { int v = myft[k]; if (v >= 1) atomicAdd(&cur[v - 1], 1); }
    __syncthreads();
    if (tid == 0) {
        int s = 0;
#pragma unroll
        for (int j = 0; j < 15; j++) { int c = cur[j]; start[j] = s; s += (c + 7) & ~7; }
        start[15] = s;
    }
    __syncthreads();
    int nnzp = start[15];
    if (tid < 15) cur[tid] = start[tid];
    const int zoff = 6250 * 200 * 4;
    for (int i = tid; i < nnzp; i += 256) perm[i] = zoff;
    __syncthreads();
#pragma unroll
    for (int k = 0; k < 16; k++) {
        int v = myft[k];
        if (v >= 1) {
            int i = tid + k * 256;
            int posv = i / 250, c = i - posv * 250;
            int p = atomicAdd(&cur[v - 1], 1);
            perm[p] = (rowb[posv] + c) * 800;
        }
    }
    __syncthreads();

    int f = tid < 200 ? tid : 199;
    const char* wb = (const char*)(wT3 + f);
    float W = W3s[px * 200 + f];
    float* o = out + 32 + ((size_t)b * NT) * 3200 + f * 16 + px;
    float R = 0.f;
    for (int j = 14; j >= 0; j--) {
        int e = start[j + 1];
        for (int i = start[j]; i < e; i += 8) {
            int4 p0 = *(const int4*)(perm + i);
            int4 p1 = *(const int4*)(perm + i + 4);
            int o0 = __builtin_amdgcn_readfirstlane(p0.x);
            int o1 = __builtin_amdgcn_readfirstlane(p0.y);
            int o2 = __builtin_amdgcn_readfirstlane(p0.z);
            int o3 = __builtin_amdgcn_readfirstlane(p0.w);
            int o4 = __builtin_amdgcn_readfirstlane(p1.x);
            int o5 = __builtin_amdgcn_readfirstlane(p1.y);
            int o6 = __builtin_amdgcn_readfirstlane(p1.z);
            int o7 = __builtin_amdgcn_readfirstlane(p1.w);
            float a0 = *(const float*)(wb + o0);
            float a1 = *(const float*)(wb + o1);
            float a2 = *(const float*)(wb + o2);
            float a3 = *(const float*)(wb + o3);
            float a4 = *(const float*)(wb + o4);
            float a5 = *(const float*)(wb + o5);
            float a6 = *(const float*)(wb + o6);
            float a7 = *(const float*)(wb + o7);
            R += ((a0 + a1) + (a2 + a3)) + ((a4 + a5) + (a6 + a7));
        }
        if (tid < 200) o[(size_t)j * 3200] = W - R;
    }
}

// ---------- pool 2x2 s2 (min ft) + pad=1, channel-last output ----------
__global__ __launch_bounds__(256) void k_pool1c(const unsigned char* __restrict__ ft1,
                                                unsigned char* __restrict__ ft1p) {
    int idx = blockIdx.x * 256 + threadIdx.x;
    if (idx >= NB * 90 * 289) return;
    int xx = idx % 17, rest = idx / 17;
    int yy = rest % 17; rest /= 17;
    int c = rest % 90; int b = rest / 90;
    int ft = 15;
    if (xx >= 1 && xx < 16 && yy >= 1 && yy < 16) {
        const unsigned char* p = ft1 + ((size_t)b * 90 + c) * 900 + (yy - 1) * 2 * 30 + (xx - 1) * 2;
        int m = p[0];
        m = min(m, (int)p[1]);
        m = min(m, (int)p[30]);
        m = min(m, (int)p[31]);
        ft = m;
    }
    ft1p[((size_t)(b * 17 + yy) * 17 + xx) * 90 + c] = (unsigned char)ft;
}

// ---------- pool 3x3 s3 (min ft) + pad=2, channel-last output ----------
__global__ __launch_bounds__(256) void k_pool2c(const unsigned char* __restrict__ ft2,
                                                unsigned char* __restrict__ ft2p) {
    int idx = blockIdx.x * 256 + threadIdx.x;
    if (idx >= NB * 250 * 64) return;
    int xx = idx % 8, rest = idx / 8;
    int yy = rest % 8; rest /= 8;
    int c = rest % 250; int b = rest / 250;
    int ft = 15;
    if (xx >= 2 && xx < 6 && yy >= 2 && yy < 6) {
        const unsigned char* p = ft2 + ((size_t)b * 250 + c) * 169 + (yy - 2) * 3 * 13 + (xx - 2) * 3;
        int m = 15;
#pragma unroll
        for (int dy = 0; dy < 3; dy++)
#pragma unroll
            for (int dx = 0; dx < 3; dx++) m = min(m, (int)p[dy * 13 + dx]);
        ft = m;
    }
    ft2p[((size_t)(b * 8 + yy) * 8 + xx) * 250 + c] = (unsigned char)ft;
}

// ---------- winner-take-all classification ----------
__global__ __launch_bounds__(256) void k_winner(const float* __restrict__ outp,
                                                float* __restrict__ outc) {
    int b = blockIdx.x, tid = threadIdx.x;
    const float* p14 = outp + 32 + ((size_t)b * NT + 14) * 3200;
    __shared__ float sv[256];
    __shared__ int   si[256];
    float m = 0.f;
    for (int j = tid; j < 3200; j += 256) {
        float v = p14[j];
        if (v > 0.f && v > m) m = v;
    }
    sv[tid] = m;
    __syncthreads();
    for (int s = 128; s > 0; s >>= 1) {
        if (tid < s) sv[tid] = fmaxf(sv[tid], sv[tid + s]);
        __syncthreads();
    }
    float vofs = 15.f * sv[0];
    __syncthreads();
    float bestv = 0.f; int besti = 0x3fffffff;
    for (int j = tid; j < 3200; j += 256) {
        float v = p14[j];
        float tot = (v > 0.f) ? v + vofs : 0.f;
        if (tot > bestv) { bestv = tot; besti = j; }
    }
    sv[tid] = bestv; si[tid] = besti;
    __syncthreads();
    for (int s = 128; s > 0; s >>= 1) {
        if (tid < s) {
            if (sv[tid + s] > sv[tid] || (sv[tid + s] == sv[tid] && si[tid + s] < si[tid])) {
                sv[tid] = sv[tid + s]; si[tid] = si[tid + s];
            }
        }
        __syncthreads();
    }
    if (tid == 0) {
        float mx = sv[0];
        int cls = (mx != 0.f) ? ((si[0] / 16) / 20) : -1;
        outc[b] = (float)cls;
    }
}

extern "C" void kernel_launch(void* const* d_in, const int* in_sizes, int n_in,
                              void* d_out, int out_size, void* d_ws, size_t ws_size,
                              hipStream_t stream) {
    const float* inp = (const float*)d_in[0];
    const float* w1  = (const float*)d_in[1];
    const float* w2  = (const float*)d_in[2];
    const float* w3  = (const float*)d_in[3];
    float* out = (float*)d_out;

    unsigned char* ws   = (unsigned char*)d_ws;
    unsigned char* ft0  = ws;
    unsigned char* ft1  = ws + 746496;
    unsigned char* ft1p = ws + 3338496;
    unsigned char* ft2  = ws + 4170816;
    unsigned char* ft2p = ws + 5522816;
    float* wT1 = (float*)(ws + 6034816);
    float* wT2 = (float*)(ws + 6352704);
    float* wT3 = (float*)(ws + 8603712);
    float* W2s = (float*)(ws + 13604544);
    float* W3s = (float*)(ws + 13605568);

    hipLaunchKernelGGL(k_zero, dim3(14), dim3(256), 0, stream, W2s);
    hipLaunchKernelGGL(k_ft0c, dim3(972), dim3(256), 0, stream, inp, ft0);
    hipLaunchKernelGGL((k_tr<90, 18, 7>),   dim3(311),  dim3(256), 0, stream, w1, wT1);
    hipLaunchKernelGGL((k_tr<250, 90, 5>),  dim3(2199), dim3(256), 0, stream, w2, wT2);
    hipLaunchKernelGGL((k_tr<200, 250, 5>), dim3(4884), dim3(256), 0, stream, w3, wT3);
    hipLaunchKernelGGL(k_colsum2, dim3(45), dim3(256), 0, stream, wT2, W2s);
    hipLaunchKernelGGL(k_w3s, dim3(16, 50), dim3(256), 0, stream, wT3, W3s);

    hipLaunchKernelGGL(k_conv1f, dim3(900, NB), dim3(128), 0, stream, ft0, wT1, ft1);
    hipLaunchKernelGGL(k_pool1c, dim3((NB * 90 * 289 + 255) / 256), dim3(256), 0, stream, ft1, ft1p);
    hipLaunchKernelGGL(k_conv2cr, dim3(169, NB), dim3(256), 0, stream, ft1p, wT2, W2s, ft2);
    hipLaunchKernelGGL(k_pool2c, dim3((NB * 250 * 64 + 255) / 256), dim3(256), 0, stream, ft2, ft2p);
    hipLaunchKernelGGL(k_conv3cr, dim3(16, NB), dim3(256), 0, stream, ft2p, wT3, W3s, out);
    hipLaunchKernelGGL(k_winner, dim3(NB), dim3(256), 0, stream, out, out);
}

// Round 8
// 228.016 us; speedup vs baseline: 26.9245x; 1.2082x over previous
//
#include <hip/hip_runtime.h>

#define NB 32
#define NT 15

// Workspace layout (byte offsets) — channel-last fire-time maps:
//  ft0  : 0        (B,36,36,18) u8 input ft, pad=2 ring          746496
//  ft1  : 746496   (B,30,30,90) u8 layer-1 ft (channel-last)    2592000
//  ft1p : 3338496  (B,17,17,90) u8 pool2x2s2 + pad=1             832320
//  ft2  : 4170816  (B,13,13,250) u8 layer-2 ft (channel-last)   1352000
//  ft2p : 5522816  (B,8,8,250)  u8 pool3x3s3 + pad=2             512000
//  wT1  : 6034816  (883,90)  f32 w1^T rows j=(r*7+x)*18+c  + 0   317888
//  wT2  : 6352704  (2251,250) f32 w2^T rows j=(r*5+x)*90+c + 0  2251008
//  wT3  : 8603712  (6251,200) f32 w3^T rows j=(r*5+x)*250+c + 0 5000832
//  W2s  : 13604544 (256) f32 col sums of wT2                       1024
//  W3s  : 13605568 (16,200) f32 per-px valid-tap col sums          12800
//  PosS : 13618368 (25,256) f32 per-position channel sums of wT2   25600
//  W2e  : 13643968 (169,256) f32 W2s minus geometric-pad sums     173056
// end 13817024

// ---------- zero W2s+W3s+PosS (contiguous 9856 floats) ----------
__global__ __launch_bounds__(256) void k_zero(float* __restrict__ p) {
    int idx = blockIdx.x * 256 + threadIdx.x;
    if (idx < 9856) p[idx] = 0.f;
}

// ---------- input fire times, channel-last ----------
__global__ __launch_bounds__(256) void k_ft0c(const float* __restrict__ inp,
                                              unsigned char* __restrict__ ft0) {
    int idx = blockIdx.x * 256 + threadIdx.x;
    if (idx >= NB * 36 * 36 * 6) return;
    int g = idx % 6, rest = idx / 6;
    int xx = rest % 36; rest /= 36;
    int yy = rest % 36; int b = rest / 36;
    unsigned char* dst = ft0 + ((size_t)(b * 36 + yy) * 36 + xx) * 18 + g * 3;
    int x = xx - 2, y = yy - 2;
    if (x >= 0 && x < 32 && y >= 0 && y < 32) {
        int c0 = 0, c1 = 0, c2 = 0;
        const float* p = inp + ((size_t)b * NT * 18 + g * 3) * 1024 + y * 32 + x;
#pragma unroll
        for (int t = 0; t < NT; t++) {
            c0 += (p[(size_t)(t * 18 + 0) * 1024] != 0.f);
            c1 += (p[(size_t)(t * 18 + 1) * 1024] != 0.f);
            c2 += (p[(size_t)(t * 18 + 2) * 1024] != 0.f);
        }
        dst[0] = (unsigned char)(15 - c0);
        dst[1] = (unsigned char)(15 - c1);
        dst[2] = (unsigned char)(15 - c2);
    } else {
        dst[0] = 15; dst[1] = 15; dst[2] = 15;
    }
}

// ---------- weight transpose: dst[j][f], j=(r*KW+x)*CIN+c, + zero row ----------
template<int F, int CIN, int KW>
__global__ __launch_bounds__(256) void k_tr(const float* __restrict__ src,
                                            float* __restrict__ dst) {
    constexpr int K = CIN * KW * KW;
    int idx = blockIdx.x * 256 + threadIdx.x;
    if (idx >= (K + 1) * F) return;
    int j = idx / F, f = idx - j * F;
    float v = 0.f;
    if (j < K) {
        int c = j % CIN, pos = j / CIN;
        v = src[(size_t)f * K + c * (KW * KW) + pos];
    }
    dst[idx] = v;
}

// ---------- column sums of wT2 -> W2s[250] ----------
__global__ __launch_bounds__(256) void k_colsum2(const float* __restrict__ wT2,
                                                 float* __restrict__ W2s) {
    int tid = threadIdx.x;
    int f = tid < 250 ? tid : 249;
    int k0 = blockIdx.x * 50;
    float acc = 0.f;
    for (int k = k0; k < k0 + 50; k++) acc += wT2[(size_t)k * 250 + f];
    if (tid < 250) atomicAdd(&W2s[tid], acc);
}

// ---------- per-position channel sums of wT2: PosS[pos][f] ----------
__global__ __launch_bounds__(256) void k_possum2(const float* __restrict__ wT2,
                                                 float* __restrict__ PosS) {
    int tid = threadIdx.x;
    int f = tid < 250 ? tid : 249;
    int pos = blockIdx.x, ch = blockIdx.y;   // 25 pos x 9 chunks of 10 ch
    float acc = 0.f;
    for (int c = ch * 10; c < ch * 10 + 10; c++)
        acc += wT2[(size_t)(pos * 90 + c) * 250 + f];
    if (tid < 250) atomicAdd(&PosS[pos * 256 + tid], acc);
}

// ---------- W2e[px][f] = W2s[f] - sum of geometric-pad PosS ----------
__global__ __launch_bounds__(256) void k_w2eff(const float* __restrict__ W2s,
                                               const float* __restrict__ PosS,
                                               float* __restrict__ W2e) {
    int tid = threadIdx.x;
    int f = tid < 250 ? tid : 249;
    int px = blockIdx.x;
    int oy = px / 13, ox = px - oy * 13;
    float s = W2s[f];
#pragma unroll
    for (int pos = 0; pos < 25; pos++) {
        int r = pos / 5, x = pos - r * 5;
        int gy = oy + r, gx = ox + x;
        if (gy == 0 || gy == 16 || gx == 0 || gx == 16) s -= PosS[pos * 256 + f];
    }
    if (tid < 250) W2e[px * 256 + tid] = s;
}

// ---------- per-px valid-tap column sums of wT3 ----------
__global__ __launch_bounds__(256) void k_w3s(const float* __restrict__ wT3,
                                             float* __restrict__ W3s) {
    int tid = threadIdx.x;
    int f = tid < 200 ? tid : 199;
    int px = blockIdx.x, ch = blockIdx.y;
    int oy = px >> 2, ox = px & 3;
    int r0 = max(0, 2 - oy), r1 = min(4, 5 - oy);
    int x0 = max(0, 2 - ox), x1 = min(4, 5 - ox);
    float acc = 0.f;
    for (int c = ch * 5; c < ch * 5 + 5; c++)
        for (int r = r0; r <= r1; r++)
            for (int x = x0; x <= x1; x++)
                acc += wT3[(size_t)((r * 5 + x) * 250 + c) * 200 + f];
    if (tid < 200) atomicAdd(&W3s[px * 200 + tid], acc);
}

// ---------- conv1: lazy per-bucket compaction, channel-last I/O ----------
__global__ __launch_bounds__(128) void k_conv1f(const unsigned char* __restrict__ ft0,
                                                const float* __restrict__ wT1,
                                                unsigned char* __restrict__ ft1) {
    __shared__ __align__(16) int list[896];
    __shared__ int cnt, pcnt;
    int tid = threadIdx.x;
    int px = blockIdx.x, b = blockIdx.y;
    int oy = px / 30, ox = px - oy * 30;
    const unsigned char* base = ft0 + ((size_t)(b * 36 + oy) * 36 + ox) * 18;
    unsigned char myft[7];
#pragma unroll
    for (int k = 0; k < 7; k++) {
        int j = tid + k * 128;
        if (j < 882) {
            int c = j % 18, pos = j / 18;
            int r = pos / 7, x = pos - r * 7;
            myft[k] = base[(r * 36 + x) * 18 + c];
        } else myft[k] = 255;
    }
    int f = tid < 90 ? tid : 89;
    const char* wb = (const char*)(wT1 + f);
    const int zoff = 882 * 90 * 4;
    float acc = 0.f; int ft = 15;
    for (int s = 0; s < 15; s++) {
        if (tid == 0) cnt = 0;
        __syncthreads();
#pragma unroll
        for (int k = 0; k < 7; k++) {
            if ((int)myft[k] == s) { int p = atomicAdd(&cnt, 1); list[p] = (tid + k * 128) * 360; }
        }
        __syncthreads();
        if (tid == 0) {
            int c0 = cnt, cp = (c0 + 7) & ~7;
            for (int i = c0; i < cp; i++) list[i] = zoff;
            pcnt = cp;
        }
        __syncthreads();
        int e = pcnt;
        for (int i = 0; i < e; i += 8) {
            int4 p0 = *(const int4*)(list + i);
            int4 p1 = *(const int4*)(list + i + 4);
            int o0 = __builtin_amdgcn_readfirstlane(p0.x);
            int o1 = __builtin_amdgcn_readfirstlane(p0.y);
            int o2 = __builtin_amdgcn_readfirstlane(p0.z);
            int o3 = __builtin_amdgcn_readfirstlane(p0.w);
            int o4 = __builtin_amdgcn_readfirstlane(p1.x);
            int o5 = __builtin_amdgcn_readfirstlane(p1.y);
            int o6 = __builtin_amdgcn_readfirstlane(p1.z);
            int o7 = __builtin_amdgcn_readfirstlane(p1.w);
            float a0 = *(const float*)(wb + o0);
            float a1 = *(const float*)(wb + o1);
            float a2 = *(const float*)(wb + o2);
            float a3 = *(const float*)(wb + o3);
            float a4 = *(const float*)(wb + o4);
            float a5 = *(const float*)(wb + o5);
            float a6 = *(const float*)(wb + o6);
            float a7 = *(const float*)(wb + o7);
            acc += ((a0 + a1) + (a2 + a3)) + ((a4 + a5) + (a6 + a7));
        }
        if (ft == 15 && acc > 15.0f) ft = s;
        if (__syncthreads_and(ft != 15)) break;
    }
    if (tid < 90) ft1[((size_t)(b * 30 + oy) * 30 + ox) * 90 + tid] = (unsigned char)ft;
}

// ---------- conv2 complement walk, geometric pads hoisted into W2e ----------
__global__ __launch_bounds__(256) void k_conv2cr(const unsigned char* __restrict__ ft1p,
                                                 const float* __restrict__ wT2,
                                                 const float* __restrict__ W2e,
                                                 unsigned char* __restrict__ ft2) {
    constexpr int PADCAP = 2250 + 15 * 8;
    __shared__ __align__(16) int perm[PADCAP];
    __shared__ int start[16], cur[16];
    int tid = threadIdx.x;
    int px = blockIdx.x, b = blockIdx.y;
    int oy = px / 13, ox = px - oy * 13;
    const unsigned char* base = ft1p + ((size_t)(b * 17 + oy) * 17 + ox) * 90;
    unsigned char myft[9];
#pragma unroll
    for (int k = 0; k < 9; k++) {
        int j = tid + k * 256;
        myft[k] = 0;
        if (j < 2250) {
            int c = j % 90, pos = j / 90;
            int r = pos / 5, x = pos - r * 5;
            int gy = oy + r, gx = ox + x;
            unsigned char v = base[(r * 17 + x) * 90 + c];
            // geometric pads excluded (W2e accounts for them)
            myft[k] = (gy == 0 || gy == 16 || gx == 0 || gx == 16) ? 0 : v;
        }
    }
    if (tid < 16) cur[tid] = 0;
    __syncthreads();
#pragma unroll
    for (int k = 0; k < 9; k++) { int v = myft[k]; if (v >= 1) atomicAdd(&cur[v - 1], 1); }
    __syncthreads();
    if (tid == 0) {
        int s = 0;
#pragma unroll
        for (int j = 0; j < 15; j++) { int c = cur[j]; start[j] = s; s += (c + 7) & ~7; }
        start[15] = s;
    }
    __syncthreads();
    int nnzp = start[15];
    if (tid < 15) cur[tid] = start[tid];
    const int zoff = 2250 * 250 * 4;
    for (int i = tid; i < nnzp; i += 256) perm[i] = zoff;
    __syncthreads();
#pragma unroll
    for (int k = 0; k < 9; k++) {
        int v = myft[k];
        if (v >= 1) { int p = atomicAdd(&cur[v - 1], 1); perm[p] = (tid + k * 256) * 1000; }
    }
    __syncthreads();

    int f = tid < 250 ? tid : 249;
    const char* wb = (const char*)(wT2 + f);
    float W = W2e[px * 256 + f];
    float R = 0.f; int ft = 15;
    for (int j = 14; j >= 0; j--) {
        int sjb = start[j], e = start[j + 1];
        for (int i = sjb; i < e; i += 8) {
            int4 p0 = *(const int4*)(perm + i);
            int4 p1 = *(const int4*)(perm + i + 4);
            int o0 = __builtin_amdgcn_readfirstlane(p0.x);
            int o1 = __builtin_amdgcn_readfirstlane(p0.y);
            int o2 = __builtin_amdgcn_readfirstlane(p0.z);
            int o3 = __builtin_amdgcn_readfirstlane(p0.w);
            int o4 = __builtin_amdgcn_readfirstlane(p1.x);
            int o5 = __builtin_amdgcn_readfirstlane(p1.y);
            int o6 = __builtin_amdgcn_readfirstlane(p1.z);
            int o7 = __builtin_amdgcn_readfirstlane(p1.w);
            float a0 = *(const float*)(wb + o0);
            float a1 = *(const float*)(wb + o1);
            float a2 = *(const float*)(wb + o2);
            float a3 = *(const float*)(wb + o3);
            float a4 = *(const float*)(wb + o4);
            float a5 = *(const float*)(wb + o5);
            float a6 = *(const float*)(wb + o6);
            float a7 = *(const float*)(wb + o7);
            R += ((a0 + a1) + (a2 + a3)) + ((a4 + a5) + (a6 + a7));
        }
        float pot = W - R;
        if (pot > 10.0f) ft = j;
        if (sjb == 0) { if (pot > 10.0f) ft = 0; break; }   // nothing below: pot constant
        if (__all(pot <= 10.0f)) break;
    }
    if (tid < 250) ft2[((size_t)(b * 13 + oy) * 13 + ox) * 250 + tid] = (unsigned char)ft;
}

// ---------- conv3 complement walk over VALID taps; stores all 15 pots ----------
__global__ __launch_bounds__(256) void k_conv3cr(const unsigned char* __restrict__ ft2p,
                                                 const float* __restrict__ wT3,
                                                 const float* __restrict__ W3s,
                                                 float* __restrict__ out) {
    constexpr int PADCAP = 4000 + 15 * 8;
    __shared__ __align__(16) int perm[PADCAP];
    __shared__ int start[16], cur[16];
    __shared__ int offs[16], rowb[16];
    int tid = threadIdx.x;
    int px = blockIdx.x, b = blockIdx.y;
    int oy = px >> 2, ox = px & 3;
    int r0 = max(0, 2 - oy), r1 = min(4, 5 - oy);
    int x0 = max(0, 2 - ox), x1 = min(4, 5 - ox);
    int VR = r1 - r0 + 1, VC = x1 - x0 + 1;
    int NP = VR * VC, NV = NP * 250;
    if (tid < NP) {
        int rv = tid / VC, xv = tid - rv * VC;
        offs[tid] = ((r0 + rv) * 8 + (x0 + xv)) * 250;
        rowb[tid] = ((r0 + rv) * 5 + (x0 + xv)) * 250;
    }
    if (tid < 16) cur[tid] = 0;
    const unsigned char* base = ft2p + ((size_t)(b * 8 + oy) * 8 + ox) * 250;
    __syncthreads();
    unsigned char myft[16];
#pragma unroll
    for (int k = 0; k < 16; k++) {
        int i = tid + k * 256;
        myft[k] = 0;
        if (i < NV) {
            int posv = i / 250, c = i - posv * 250;
            myft[k] = base[offs[posv] + c];
        }
    }
#pragma unroll
    for (int k = 0; k < 16; k++) { int v = myft[k]; if (v >= 1) atomicAdd(&cur[v - 1], 1); }
    __syncthreads();
    if (tid == 0) {
        int s = 0;
#pragma unroll
        for (int j = 0; j < 15; j++) { int c = cur[j]; start[j] = s; s += (c + 7) & ~7; }
        start[15] = s;
    }
    __syncthreads();
    int nnzp = start[15];
    if (tid < 15) cur[tid] = start[tid];
    const int zoff = 6250 * 200 * 4;
    for (int i = tid; i < nnzp; i += 256) perm[i] = zoff;
    __syncthreads();
#pragma unroll
    for (int k = 0; k < 16; k++) {
        int v = myft[k];
        if (v >= 1) {
            int i = tid + k * 256;
            int posv = i / 250, c = i - posv * 250;
            int p = atomicAdd(&cur[v - 1], 1);
            perm[p] = (rowb[posv] + c) * 800;
        }
    }
    __syncthreads();

    int f = tid < 200 ? tid : 199;
    const char* wb = (const char*)(wT3 + f);
    float W = W3s[px * 200 + f];
    float* o = out + 32 + ((size_t)b * NT) * 3200 + f * 16 + px;
    float R = 0.f;
    for (int j = 14; j >= 0; j--) {
        int sjb = start[j], e = start[j + 1];
        for (int i = sjb; i < e; i += 8) {
            int4 p0 = *(const int4*)(perm + i);
            int4 p1 = *(const int4*)(perm + i + 4);
            int o0 = __builtin_amdgcn_readfirstlane(p0.x);
            int o1 = __builtin_amdgcn_readfirstlane(p0.y);
            int o2 = __builtin_amdgcn_readfirstlane(p0.z);
            int o3 = __builtin_amdgcn_readfirstlane(p0.w);
            int o4 = __builtin_amdgcn_readfirstlane(p1.x);
            int o5 = __builtin_amdgcn_readfirstlane(p1.y);
            int o6 = __builtin_amdgcn_readfirstlane(p1.z);
            int o7 = __builtin_amdgcn_readfirstlane(p1.w);
            float a0 = *(const float*)(wb + o0);
            float a1 = *(const float*)(wb + o1);
            float a2 = *(const float*)(wb + o2);
            float a3 = *(const float*)(wb + o3);
            float a4 = *(const float*)(wb + o4);
            float a5 = *(const float*)(wb + o5);
            float a6 = *(const float*)(wb + o6);
            float a7 = *(const float*)(wb + o7);
            R += ((a0 + a1) + (a2 + a3)) + ((a4 + a5) + (a6 + a7));
        }
        float pot = W - R;
        if (tid < 200) o[(size_t)j * 3200] = pot;
        if (sjb == 0) {     // nothing below: remaining pots identical
            for (int jj = j - 1; jj >= 0; jj--)
                if (tid < 200) o[(size_t)jj * 3200] = pot;
            break;
        }
    }
}

// ---------- pool 2x2 s2 (min ft) + pad=1, channel-last in/out ----------
__global__ __launch_bounds__(256) void k_pool1c(const unsigned char* __restrict__ ft1,
                                                unsigned char* __restrict__ ft1p) {
    int idx = blockIdx.x * 256 + threadIdx.x;
    if (idx >= NB * 17 * 17 * 90) return;
    int c = idx % 90, rest = idx / 90;
    int xx = rest % 17; rest /= 17;
    int yy = rest % 17; int b = rest / 17;
    int ft = 15;
    if (xx >= 1 && xx < 16 && yy >= 1 && yy < 16) {
        const unsigned char* p = ft1 + ((size_t)(b * 30 + (yy - 1) * 2) * 30 + (xx - 1) * 2) * 90 + c;
        int m = p[0];
        m = min(m, (int)p[90]);
        m = min(m, (int)p[30 * 90]);
        m = min(m, (int)p[31 * 90]);
        ft = m;
    }
    ft1p[idx] = (unsigned char)ft;
}

// ---------- pool 3x3 s3 (min ft) + pad=2, channel-last in/out ----------
__global__ __launch_bounds__(256) void k_pool2c(const unsigned char* __restrict__ ft2,
                                                unsigned char* __restrict__ ft2p) {
    int idx = blockIdx.x * 256 + threadIdx.x;
    if (idx >= NB * 8 * 8 * 250) return;
    int c = idx % 250, rest = idx / 250;
    int xx = rest % 8; rest /= 8;
    int yy = rest % 8; int b = rest / 8;
    int ft = 15;
    if (xx >= 2 && xx < 6 && yy >= 2 && yy < 6) {
        const unsigned char* p = ft2 + ((size_t)(b * 13 + (yy - 2) * 3) * 13 + (xx - 2) * 3) * 250 + c;
        int m = 15;
#pragma unroll
        for (int dy = 0; dy < 3; dy++)
#pragma unroll
            for (int dx = 0; dx < 3; dx++) m = min(m, (int)p[(dy * 13 + dx) * 250]);
        ft = m;
    }
    ft2p[idx] = (unsigned char)ft;
}

// ---------- winner-take-all classification ----------
__global__ __launch_bounds__(256) void k_winner(const float* __restrict__ outp,
                                                float* __restrict__ outc) {
    int b = blockIdx.x, tid = threadIdx.x;
    const float* p14 = outp + 32 + ((size_t)b * NT + 14) * 3200;
    __shared__ float sv[256];
    __shared__ int   si[256];
    float m = 0.f;
    for (int j = tid; j < 3200; j += 256) {
        float v = p14[j];
        if (v > 0.f && v > m) m = v;
    }
    sv[tid] = m;
    __syncthreads();
    for (int s = 128; s > 0; s >>= 1) {
        if (tid < s) sv[tid] = fmaxf(sv[tid], sv[tid + s]);
        __syncthreads();
    }
    float vofs = 15.f * sv[0];
    __syncthreads();
    float bestv = 0.f; int besti = 0x3fffffff;
    for (int j = tid; j < 3200; j += 256) {
        float v = p14[j];
        float tot = (v > 0.f) ? v + vofs : 0.f;
        if (tot > bestv) { bestv = tot; besti = j; }
    }
    sv[tid] = bestv; si[tid] = besti;
    __syncthreads();
    for (int s = 128; s > 0; s >>= 1) {
        if (tid < s) {
            if (sv[tid + s] > sv[tid] || (sv[tid + s] == sv[tid] && si[tid + s] < si[tid])) {
                sv[tid] = sv[tid + s]; si[tid] = si[tid + s];
            }
        }
        __syncthreads();
    }
    if (tid == 0) {
        float mx = sv[0];
        int cls = (mx != 0.f) ? ((si[0] / 16) / 20) : -1;
        outc[b] = (float)cls;
    }
}

extern "C" void kernel_launch(void* const* d_in, const int* in_sizes, int n_in,
                              void* d_out, int out_size, void* d_ws, size_t ws_size,
                              hipStream_t stream) {
    const float* inp = (const float*)d_in[0];
    const float* w1  = (const float*)d_in[1];
    const float* w2  = (const float*)d_in[2];
    const float* w3  = (const float*)d_in[3];
    float* out = (float*)d_out;

    unsigned char* ws   = (unsigned char*)d_ws;
    unsigned char* ft0  = ws;
    unsigned char* ft1  = ws + 746496;
    unsigned char* ft1p = ws + 3338496;
    unsigned char* ft2  = ws + 4170816;
    unsigned char* ft2p = ws + 5522816;
    float* wT1  = (float*)(ws + 6034816);
    float* wT2  = (float*)(ws + 6352704);
    float* wT3  = (float*)(ws + 8603712);
    float* W2s  = (float*)(ws + 13604544);
    float* W3s  = (float*)(ws + 13605568);
    float* PosS = (float*)(ws + 13618368);
    float* W2e  = (float*)(ws + 13643968);

    hipLaunchKernelGGL(k_zero, dim3(39), dim3(256), 0, stream, W2s);
    hipLaunchKernelGGL(k_ft0c, dim3(972), dim3(256), 0, stream, inp, ft0);
    hipLaunchKernelGGL((k_tr<90, 18, 7>),   dim3(311),  dim3(256), 0, stream, w1, wT1);
    hipLaunchKernelGGL((k_tr<250, 90, 5>),  dim3(2199), dim3(256), 0, stream, w2, wT2);
    hipLaunchKernelGGL((k_tr<200, 250, 5>), dim3(4884), dim3(256), 0, stream, w3, wT3);
    hipLaunchKernelGGL(k_colsum2, dim3(45), dim3(256), 0, stream, wT2, W2s);
    hipLaunchKernelGGL(k_possum2, dim3(25, 9), dim3(256), 0, stream, wT2, PosS);
    hipLaunchKernelGGL(k_w3s, dim3(16, 50), dim3(256), 0, stream, wT3, W3s);
    hipLaunchKernelGGL(k_w2eff, dim3(169), dim3(256), 0, stream, W2s, PosS, W2e);

    hipLaunchKernelGGL(k_conv1f, dim3(900, NB), dim3(128), 0, stream, ft0, wT1, ft1);
    hipLaunchKernelGGL(k_pool1c, dim3((NB * 17 * 17 * 90 + 255) / 256), dim3(256), 0, stream, ft1, ft1p);
    hipLaunchKernelGGL(k_conv2cr, dim3(169, NB), dim3(256), 0, stream, ft1p, wT2, W2e, ft2);
    hipLaunchKernelGGL(k_pool2c, dim3((NB * 8 * 8 * 250 + 255) / 256), dim3(256), 0, stream, ft2, ft2p);
    hipLaunchKernelGGL(k_conv3cr, dim3(16, NB), dim3(256), 0, stream, ft2p, wT3, W3s, out);
    hipLaunchKernelGGL(k_winner, dim3(NB), dim3(256), 0, stream, out, out);
}

// Round 9
// 182.309 us; speedup vs baseline: 33.6748x; 1.2507x over previous
//
#include <hip/hip_runtime.h>

#define NB 32
#define NT 15

// Workspace layout (byte offsets) — channel-last fire-time maps:
//  ft0  : 0        (B,36,36,18) u8 input ft, pad=2 ring          746496
//  ft1  : 746496   (B,30,30,90) u8 layer-1 ft                   2592000
//  ft1p : 3338496  (B,17,17,90) u8 pool2x2s2, pad ring = 0       832320
//  ft2  : 4170816  (B,13,13,250) u8 layer-2 ft                  1352000
//  ft2p : 5522816  (B,8,8,250)  u8 pool3x3s3 + pad=2             512000
//  wT1  : 6034816  (883,90)  f32 w1^T rows j=(r*7+x)*18+c  + 0   317888
//  wT2  : 6352704  (2251,250) f32 w2^T rows j=(r*5+x)*90+c + 0  2251008
//  wT3  : 8603712  (6251,200) f32 w3^T rows j=(r*5+x)*250+c + 0 5000832
//  W3s  : 13605568 (16,200) f32 per-px valid-tap col sums         12800
//  PosS : 13618368 (25,256) f32 per-position channel sums of wT2  25600
//  W2e  : 13643968 (169,256) f32 effective tap-sums (pads excl)  173056
//  Pmin1: 13817024 (64) f32 partial mins of w1                      256
//  m1   : 13817280 (1)  f32 global min of w1                          4

// ---------- zero W3s+PosS (contiguous 9600 floats) ----------
__global__ __launch_bounds__(256) void k_zero(float* __restrict__ p) {
    int idx = blockIdx.x * 256 + threadIdx.x;
    if (idx < 9600) p[idx] = 0.f;
}

// ---------- input fire times, channel-last, xx-fastest for coalescing ----------
__global__ __launch_bounds__(256) void k_ft0c(const float* __restrict__ inp,
                                              unsigned char* __restrict__ ft0) {
    int idx = blockIdx.x * 256 + threadIdx.x;
    if (idx >= NB * 36 * 36 * 6) return;
    int xx = idx % 36, rest = idx / 36;
    int yy = rest % 36; rest /= 36;
    int g = rest % 6;  int b = rest / 6;
    unsigned char* dst = ft0 + ((size_t)(b * 36 + yy) * 36 + xx) * 18 + g * 3;
    int x = xx - 2, y = yy - 2;
    if (x >= 0 && x < 32 && y >= 0 && y < 32) {
        int c0 = 0, c1 = 0, c2 = 0;
        const float* p = inp + ((size_t)b * NT * 18 + g * 3) * 1024 + y * 32 + x;
#pragma unroll
        for (int t = 0; t < NT; t++) {
            c0 += (p[(size_t)(t * 18 + 0) * 1024] != 0.f);
            c1 += (p[(size_t)(t * 18 + 1) * 1024] != 0.f);
            c2 += (p[(size_t)(t * 18 + 2) * 1024] != 0.f);
        }
        dst[0] = (unsigned char)(15 - c0);
        dst[1] = (unsigned char)(15 - c1);
        dst[2] = (unsigned char)(15 - c2);
    } else {
        dst[0] = 15; dst[1] = 15; dst[2] = 15;
    }
}

// ---------- merged weight transposes ----------
__device__ __forceinline__ void tr_body(const float* __restrict__ src, float* __restrict__ dst,
                                        int F, int CIN, int KW, int idx) {
    int K = CIN * KW * KW;
    if (idx >= (K + 1) * F) return;
    int j = idx / F, f = idx - j * F;
    float v = 0.f;
    if (j < K) {
        int c = j % CIN, pos = j / CIN;
        v = src[(size_t)f * K + c * (KW * KW) + pos];
    }
    dst[idx] = v;
}
__global__ __launch_bounds__(256) void k_tr3(const float* __restrict__ w1, const float* __restrict__ w2,
                                             const float* __restrict__ w3,
                                             float* __restrict__ wT1, float* __restrict__ wT2,
                                             float* __restrict__ wT3) {
    int b = blockIdx.x;
    if (b < 311)       tr_body(w1, wT1, 90, 18, 7, b * 256 + threadIdx.x);
    else if (b < 2510) tr_body(w2, wT2, 250, 90, 5, (b - 311) * 256 + threadIdx.x);
    else               tr_body(w3, wT3, 200, 250, 5, (b - 2510) * 256 + threadIdx.x);
}

// ---------- merged sums: PosS (225 blks) + W3s (800 blks) + min(w1) partials (40 blks) ----------
__global__ __launch_bounds__(256) void k_sums(const float* __restrict__ wT2, const float* __restrict__ wT3,
                                              const float* __restrict__ w1,
                                              float* __restrict__ PosS, float* __restrict__ W3s,
                                              float* __restrict__ Pmin1) {
    int b = blockIdx.x, tid = threadIdx.x;
    if (b < 225) {
        int pos = b % 25, ch = b / 25;
        int f = tid < 250 ? tid : 249;
        float acc = 0.f;
        for (int c = ch * 10; c < ch * 10 + 10; c++)
            acc += wT2[(size_t)(pos * 90 + c) * 250 + f];
        if (tid < 250) atomicAdd(&PosS[pos * 256 + tid], acc);
    } else if (b < 1025) {
        int bb = b - 225;
        int px = bb % 16, ch = bb / 16;
        int f = tid < 200 ? tid : 199;
        int oy = px >> 2, ox = px & 3;
        int r0 = max(0, 2 - oy), r1 = min(4, 5 - oy);
        int x0 = max(0, 2 - ox), x1 = min(4, 5 - ox);
        float acc = 0.f;
        for (int c = ch * 5; c < ch * 5 + 5; c++)
            for (int r = r0; r <= r1; r++)
                for (int x = x0; x <= x1; x++)
                    acc += wT3[(size_t)((r * 5 + x) * 250 + c) * 200 + f];
        if (tid < 200) atomicAdd(&W3s[px * 200 + tid], acc);
    } else {
        int bb = b - 1025;
        __shared__ float wm[4];
        float m = 1e30f;
#pragma unroll
        for (int k = 0; k < 8; k++) {
            int i = bb * 2048 + k * 256 + tid;
            if (i < 90 * 882) m = fminf(m, w1[i]);
        }
        for (int o = 32; o > 0; o >>= 1) m = fminf(m, __shfl_down(m, o));
        if ((tid & 63) == 0) wm[tid >> 6] = m;
        __syncthreads();
        if (tid == 0) Pmin1[bb] = fminf(fminf(wm[0], wm[1]), fminf(wm[2], wm[3]));
    }
}

// ---------- W2e[px][f] = sum of non-pad PosS; block 169 = min finisher ----------
__global__ __launch_bounds__(256) void k_w2eff(const float* __restrict__ PosS,
                                               const float* __restrict__ Pmin1,
                                               float* __restrict__ W2e, float* __restrict__ m1) {
    int b = blockIdx.x, tid = threadIdx.x;
    if (b == 169) {
        if (tid < 64) {
            float m = (tid < 40) ? Pmin1[tid] : 1e30f;
            for (int o = 32; o > 0; o >>= 1) m = fminf(m, __shfl_down(m, o));
            if (tid == 0) m1[0] = m;
        }
        return;
    }
    int f = tid < 250 ? tid : 249;
    int oy = b / 13, ox = b - oy * 13;
    float s = 0.f;
#pragma unroll
    for (int pos = 0; pos < 25; pos++) {
        int r = pos / 5, x = pos - r * 5;
        int gy = oy + r, gx = ox + x;
        if (!(gy == 0 || gy == 16 || gx == 0 || gx == 16)) s += PosS[pos * 256 + f];
    }
    if (tid < 250) W2e[b * 256 + tid] = s;
}

// ---------- conv1: cnt0*m1 bound fast path; exact walk fallback ----------
__global__ __launch_bounds__(128) void k_conv1f(const unsigned char* __restrict__ ft0,
                                                const float* __restrict__ wT1,
                                                const float* __restrict__ m1p,
                                                unsigned char* __restrict__ ft1) {
    __shared__ __align__(16) int list[896];
    __shared__ int cnt, pcnt, cnt0s;
    int tid = threadIdx.x;
    int px = blockIdx.x, b = blockIdx.y;
    int oy = px / 30, ox = px - oy * 30;
    const unsigned char* base = ft0 + ((size_t)(b * 36 + oy) * 36 + ox) * 18;
    if (tid == 0) cnt0s = 0;
    unsigned char myft[7];
    int nz = 0;
#pragma unroll
    for (int k = 0; k < 7; k++) {
        int j = tid + k * 128;
        if (j < 882) {
            int r = j / 126;                    // offset = j + (36-7)*18 * r
            myft[k] = base[j + 522 * r];
        } else myft[k] = 255;
        nz += (myft[k] == 0);
    }
    for (int o = 32; o > 0; o >>= 1) nz += __shfl_down(nz, o);
    __syncthreads();
    if ((tid & 63) == 0) atomicAdd(&cnt0s, nz);
    __syncthreads();
    // sound bound: acc_f(0) >= cnt0 * min(w1) for every f
    if ((float)cnt0s * m1p[0] > 15.0f) {
        if (tid < 90) ft1[((size_t)(b * 30 + oy) * 30 + ox) * 90 + tid] = 0;
        return;
    }
    // exact fallback: lazy per-bucket compaction walk
    int f = tid < 90 ? tid : 89;
    const char* wb = (const char*)(wT1 + f);
    const int zoff = 882 * 90 * 4;
    float acc = 0.f; int ft = 15;
    for (int s = 0; s < 15; s++) {
        if (tid == 0) cnt = 0;
        __syncthreads();
#pragma unroll
        for (int k = 0; k < 7; k++) {
            if ((int)myft[k] == s) { int p = atomicAdd(&cnt, 1); list[p] = (tid + k * 128) * 360; }
        }
        __syncthreads();
        if (tid == 0) {
            int c0 = cnt, cp = (c0 + 7) & ~7;
            for (int i = c0; i < cp; i++) list[i] = zoff;
            pcnt = cp;
        }
        __syncthreads();
        int e = pcnt;
        for (int i = 0; i < e; i += 8) {
            int4 p0 = *(const int4*)(list + i);
            int4 p1 = *(const int4*)(list + i + 4);
            int o0 = __builtin_amdgcn_readfirstlane(p0.x);
            int o1 = __builtin_amdgcn_readfirstlane(p0.y);
            int o2 = __builtin_amdgcn_readfirstlane(p0.z);
            int o3 = __builtin_amdgcn_readfirstlane(p0.w);
            int o4 = __builtin_amdgcn_readfirstlane(p1.x);
            int o5 = __builtin_amdgcn_readfirstlane(p1.y);
            int o6 = __builtin_amdgcn_readfirstlane(p1.z);
            int o7 = __builtin_amdgcn_readfirstlane(p1.w);
            float a0 = *(const float*)(wb + o0);
            float a1 = *(const float*)(wb + o1);
            float a2 = *(const float*)(wb + o2);
            float a3 = *(const float*)(wb + o3);
            float a4 = *(const float*)(wb + o4);
            float a5 = *(const float*)(wb + o5);
            float a6 = *(const float*)(wb + o6);
            float a7 = *(const float*)(wb + o7);
            acc += ((a0 + a1) + (a2 + a3)) + ((a4 + a5) + (a6 + a7));
        }
        if (ft == 15 && acc > 15.0f) ft = s;
        if (__syncthreads_and(ft != 15)) break;
    }
    if (tid < 90) ft1[((size_t)(b * 30 + oy) * 30 + ox) * 90 + tid] = (unsigned char)ft;
}

// ---------- conv2: complement-empty fast path; exact walk fallback ----------
__global__ __launch_bounds__(256) void k_conv2cr(const unsigned char* __restrict__ ft1p,
                                                 const float* __restrict__ wT2,
                                                 const float* __restrict__ W2e,
                                                 unsigned char* __restrict__ ft2) {
    constexpr int PADCAP = 2250 + 15 * 8;
    __shared__ __align__(16) int perm[PADCAP];
    __shared__ int start[16], cur[16];
    __shared__ int cntCs;
    int tid = threadIdx.x;
    int px = blockIdx.x, b = blockIdx.y;
    int oy = px / 13, ox = px - oy * 13;
    const unsigned char* base = ft1p + ((size_t)(b * 17 + oy) * 17 + ox) * 90;
    if (tid == 0) cntCs = 0;
    if (tid < 16) cur[tid] = 0;
    unsigned char myft[9];
    int nc = 0;
#pragma unroll
    for (int k = 0; k < 9; k++) {
        int j = tid + k * 256;
        myft[k] = 0;
        if (j < 2250) {
            int r = j / 450;                    // offset = j + (17-5)*90 * r
            myft[k] = base[j + 1080 * r];       // pad ring stored as 0
        }
        nc += (myft[k] >= 1);
    }
    for (int o = 32; o > 0; o >>= 1) nc += __shfl_down(nc, o);
    __syncthreads();
    if ((tid & 63) == 0) atomicAdd(&cntCs, nc);
    __syncthreads();
    int f = tid < 250 ? tid : 249;
    float W = W2e[px * 256 + f];
    if (cntCs == 0) {   // pot(t) == W for all t — exact
        if (tid < 250) ft2[((size_t)(b * 13 + oy) * 13 + ox) * 250 + tid] = (W > 10.0f) ? 0 : 15;
        return;
    }
    // exact fallback: complement hist/scatter/walk
#pragma unroll
    for (int k = 0; k < 9; k++) { int v = myft[k]; if (v >= 1) atomicAdd(&cur[v - 1], 1); }
    __syncthreads();
    if (tid == 0) {
        int s = 0;
#pragma unroll
        for (int j = 0; j < 15; j++) { int c = cur[j]; start[j] = s; s += (c + 7) & ~7; }
        start[15] = s;
    }
    __syncthreads();
    int nnzp = start[15];
    if (tid < 15) cur[tid] = start[tid];
    const int zoff = 2250 * 250 * 4;
    for (int i = tid; i < nnzp; i += 256) perm[i] = zoff;
    __syncthreads();
#pragma unroll
    for (int k = 0; k < 9; k++) {
        int v = myft[k];
        if (v >= 1) { int p = atomicAdd(&cur[v - 1], 1); perm[p] = (tid + k * 256) * 1000; }
    }
    __syncthreads();
    const char* wb = (const char*)(wT2 + f);
    float R = 0.f; int ft = 15;
    for (int j = 14; j >= 0; j--) {
        int sjb = start[j], e = start[j + 1];
        for (int i = sjb; i < e; i += 8) {
            int4 p0 = *(const int4*)(perm + i);
            int4 p1 = *(const int4*)(perm + i + 4);
            int o0 = __builtin_amdgcn_readfirstlane(p0.x);
            int o1 = __builtin_amdgcn_readfirstlane(p0.y);
            int o2 = __builtin_amdgcn_readfirstlane(p0.z);
            int o3 = __builtin_amdgcn_readfirstlane(p0.w);
            int o4 = __builtin_amdgcn_readfirstlane(p1.x);
            int o5 = __builtin_amdgcn_readfirstlane(p1.y);
            int o6 = __builtin_amdgcn_readfirstlane(p1.z);
            int o7 = __builtin_amdgcn_readfirstlane(p1.w);
            float a0 = *(const float*)(wb + o0);
            float a1 = *(const float*)(wb + o1);
            float a2 = *(const float*)(wb + o2);
            float a3 = *(const float*)(wb + o3);
            float a4 = *(const float*)(wb + o4);
            float a5 = *(const float*)(wb + o5);
            float a6 = *(const float*)(wb + o6);
            float a7 = *(const float*)(wb + o7);
            R += ((a0 + a1) + (a2 + a3)) + ((a4 + a5) + (a6 + a7));
        }
        float pot = W - R;
        if (pot > 10.0f) ft = j;
        if (sjb == 0) { if (pot > 10.0f) ft = 0; break; }
        if (__all(pot <= 10.0f)) break;
    }
    if (tid < 250) ft2[((size_t)(b * 13 + oy) * 13 + ox) * 250 + tid] = (unsigned char)ft;
}

// ---------- conv3 complement walk over VALID taps; stores all 15 pots ----------
__global__ __launch_bounds__(256) void k_conv3cr(const unsigned char* __restrict__ ft2p,
                                                 const float* __restrict__ wT3,
                                                 const float* __restrict__ W3s,
                                                 float* __restrict__ out) {
    constexpr int PADCAP = 4000 + 15 * 8;
    __shared__ __align__(16) int perm[PADCAP];
    __shared__ int start[16], cur[16];
    __shared__ int offs[16], rowb[16];
    int tid = threadIdx.x;
    int px = blockIdx.x, b = blockIdx.y;
    int oy = px >> 2, ox = px & 3;
    int r0 = max(0, 2 - oy), r1 = min(4, 5 - oy);
    int x0 = max(0, 2 - ox), x1 = min(4, 5 - ox);
    int VR = r1 - r0 + 1, VC = x1 - x0 + 1;
    int NP = VR * VC, NV = NP * 250;
    if (tid < NP) {
        int rv = tid / VC, xv = tid - rv * VC;
        offs[tid] = ((r0 + rv) * 8 + (x0 + xv)) * 250;
        rowb[tid] = ((r0 + rv) * 5 + (x0 + xv)) * 250;
    }
    if (tid < 16) cur[tid] = 0;
    const unsigned char* base = ft2p + ((size_t)(b * 8 + oy) * 8 + ox) * 250;
    __syncthreads();
    unsigned char myft[16];
#pragma unroll
    for (int k = 0; k < 16; k++) {
        int i = tid + k * 256;
        myft[k] = 0;
        if (i < NV) {
            int posv = i / 250, c = i - posv * 250;
            myft[k] = base[offs[posv] + c];
        }
    }
#pragma unroll
    for (int k = 0; k < 16; k++) { int v = myft[k]; if (v >= 1) atomicAdd(&cur[v - 1], 1); }
    __syncthreads();
    if (tid == 0) {
        int s = 0;
#pragma unroll
        for (int j = 0; j < 15; j++) { int c = cur[j]; start[j] = s; s += (c + 7) & ~7; }
        start[15] = s;
    }
    __syncthreads();
    int nnzp = start[15];
    if (tid < 15) cur[tid] = start[tid];
    const int zoff = 6250 * 200 * 4;
    for (int i = tid; i < nnzp; i += 256) perm[i] = zoff;
    __syncthreads();
#pragma unroll
    for (int k = 0; k < 16; k++) {
        int v = myft[k];
        if (v >= 1) {
            int i = tid + k * 256;
            int posv = i / 250, c = i - posv * 250;
            int p = atomicAdd(&cur[v - 1], 1);
            perm[p] = (rowb[posv] + c) * 800;
        }
    }
    __syncthreads();

    int f = tid < 200 ? tid : 199;
    const char* wb = (const char*)(wT3 + f);
    float W = W3s[px * 200 + f];
    float* o = out + 32 + ((size_t)b * NT) * 3200 + f * 16 + px;
    float R = 0.f;
    for (int j = 14; j >= 0; j--) {
        int sjb = start[j], e = start[j + 1];
        for (int i = sjb; i < e; i += 8) {
            int4 p0 = *(const int4*)(perm + i);
            int4 p1 = *(const int4*)(perm + i + 4);
            int o0 = __builtin_amdgcn_readfirstlane(p0.x);
            int o1 = __builtin_amdgcn_readfirstlane(p0.y);
            int o2 = __builtin_amdgcn_readfirstlane(p0.z);
            int o3 = __builtin_amdgcn_readfirstlane(p0.w);
            int o4 = __builtin_amdgcn_readfirstlane(p1.x);
            int o5 = __builtin_amdgcn_readfirstlane(p1.y);
            int o6 = __builtin_amdgcn_readfirstlane(p1.z);
            int o7 = __builtin_amdgcn_readfirstlane(p1.w);
            float a0 = *(const float*)(wb + o0);
            float a1 = *(const float*)(wb + o1);
            float a2 = *(const float*)(wb + o2);
            float a3 = *(const float*)(wb + o3);
            float a4 = *(const float*)(wb + o4);
            float a5 = *(const float*)(wb + o5);
            float a6 = *(const float*)(wb + o6);
            float a7 = *(const float*)(wb + o7);
            R += ((a0 + a1) + (a2 + a3)) + ((a4 + a5) + (a6 + a7));
        }
        float pot = W - R;
        if (tid < 200) o[(size_t)j * 3200] = pot;
        if (sjb == 0) {
            for (int jj = j - 1; jj >= 0; jj--)
                if (tid < 200) o[(size_t)jj * 3200] = pot;
            break;
        }
    }
}

// ---------- pool 2x2 s2 (min ft); pad ring = 0 (pads excluded via W2e) ----------
__global__ __launch_bounds__(256) void k_pool1c(const unsigned char* __restrict__ ft1,
                                                unsigned char* __restrict__ ft1p) {
    int idx = blockIdx.x * 256 + threadIdx.x;
    if (idx >= NB * 17 * 17 * 90) return;
    int c = idx % 90, rest = idx / 90;
    int xx = rest % 17; rest /= 17;
    int yy = rest % 17; int b = rest / 17;
    int ft = 0;
    if (xx >= 1 && xx < 16 && yy >= 1 && yy < 16) {
        const unsigned char* p = ft1 + ((size_t)(b * 30 + (yy - 1) * 2) * 30 + (xx - 1) * 2) * 90 + c;
        int m = p[0];
        m = min(m, (int)p[90]);
        m = min(m, (int)p[30 * 90]);
        m = min(m, (int)p[31 * 90]);
        ft = m;
    }
    ft1p[idx] = (unsigned char)ft;
}

// ---------- pool 3x3 s3 (min ft) + pad=2 (pads never read by conv3) ----------
__global__ __launch_bounds__(256) void k_pool2c(const unsigned char* __restrict__ ft2,
                                                unsigned char* __restrict__ ft2p) {
    int idx = blockIdx.x * 256 + threadIdx.x;
    if (idx >= NB * 8 * 8 * 250) return;
    int c = idx % 250, rest = idx / 250;
    int xx = rest % 8; rest /= 8;
    int yy = rest % 8; int b = rest / 8;
    int ft = 15;
    if (xx >= 2 && xx < 6 && yy >= 2 && yy < 6) {
        const unsigned char* p = ft2 + ((size_t)(b * 13 + (yy - 2) * 3) * 13 + (xx - 2) * 3) * 250 + c;
        int m = 15;
#pragma unroll
        for (int dy = 0; dy < 3; dy++)
#pragma unroll
            for (int dx = 0; dx < 3; dx++) m = min(m, (int)p[(dy * 13 + dx) * 250]);
        ft = m;
    }
    ft2p[idx] = (unsigned char)ft;
}

// ---------- winner-take-all classification ----------
__global__ __launch_bounds__(256) void k_winner(const float* __restrict__ outp,
                                                float* __restrict__ outc) {
    int b = blockIdx.x, tid = threadIdx.x;
    const float* p14 = outp + 32 + ((size_t)b * NT + 14) * 3200;
    __shared__ float sv[256];
    __shared__ int   si[256];
    float m = 0.f;
    for (int j = tid; j < 3200; j += 256) {
        float v = p14[j];
        if (v > 0.f && v > m) m = v;
    }
    sv[tid] = m;
    __syncthreads();
    for (int s = 128; s > 0; s >>= 1) {
        if (tid < s) sv[tid] = fmaxf(sv[tid], sv[tid + s]);
        __syncthreads();
    }
    float vofs = 15.f * sv[0];
    __syncthreads();
    float bestv = 0.f; int besti = 0x3fffffff;
    for (int j = tid; j < 3200; j += 256) {
        float v = p14[j];
        float tot = (v > 0.f) ? v + vofs : 0.f;
        if (tot > bestv) { bestv = tot; besti = j; }
    }
    sv[tid] = bestv; si[tid] = besti;
    __syncthreads();
    for (int s = 128; s > 0; s >>= 1) {
        if (tid < s) {
            if (sv[tid + s] > sv[tid] || (sv[tid + s] == sv[tid] && si[tid + s] < si[tid])) {
                sv[tid] = sv[tid + s]; si[tid] = si[tid + s];
            }
        }
        __syncthreads();
    }
    if (tid == 0) {
        float mx = sv[0];
        int cls = (mx != 0.f) ? ((si[0] / 16) / 20) : -1;
        outc[b] = (float)cls;
    }
}

extern "C" void kernel_launch(void* const* d_in, const int* in_sizes, int n_in,
                              void* d_out, int out_size, void* d_ws, size_t ws_size,
                              hipStream_t stream) {
    const float* inp = (const float*)d_in[0];
    const float* w1  = (const float*)d_in[1];
    const float* w2  = (const float*)d_in[2];
    const float* w3  = (const float*)d_in[3];
    float* out = (float*)d_out;

    unsigned char* ws   = (unsigned char*)d_ws;
    unsigned char* ft0  = ws;
    unsigned char* ft1  = ws + 746496;
    unsigned char* ft1p = ws + 3338496;
    unsigned char* ft2  = ws + 4170816;
    unsigned char* ft2p = ws + 5522816;
    float* wT1   = (float*)(ws + 6034816);
    float* wT2   = (float*)(ws + 6352704);
    float* wT3   = (float*)(ws + 8603712);
    float* W3s   = (float*)(ws + 13605568);
    float* PosS  = (float*)(ws + 13618368);
    float* W2e   = (float*)(ws + 13643968);
    float* Pmin1 = (float*)(ws + 13817024);
    float* m1    = (float*)(ws + 13817280);

    hipLaunchKernelGGL(k_zero, dim3(38), dim3(256), 0, stream, W3s);
    hipLaunchKernelGGL(k_ft0c, dim3(972), dim3(256), 0, stream, inp, ft0);
    hipLaunchKernelGGL(k_tr3, dim3(7394), dim3(256), 0, stream, w1, w2, w3, wT1, wT2, wT3);
    hipLaunchKernelGGL(k_sums, dim3(1065), dim3(256), 0, stream, wT2, wT3, w1, PosS, W3s, Pmin1);
    hipLaunchKernelGGL(k_w2eff, dim3(170), dim3(256), 0, stream, PosS, Pmin1, W2e, m1);

    hipLaunchKernelGGL(k_conv1f, dim3(900, NB), dim3(128), 0, stream, ft0, wT1, m1, ft1);
    hipLaunchKernelGGL(k_pool1c, dim3((NB * 17 * 17 * 90 + 255) / 256), dim3(256), 0, stream, ft1, ft1p);
    hipLaunchKernelGGL(k_conv2cr, dim3(169, NB), dim3(256), 0, stream, ft1p, wT2, W2e, ft2);
    hipLaunchKernelGGL(k_pool2c, dim3((NB * 8 * 8 * 250 + 255) / 256), dim3(256), 0, stream, ft2, ft2p);
    hipLaunchKernelGGL(k_conv3cr, dim3(16, NB), dim3(256), 0, stream, ft2p, wT3, W3s, out);
    hipLaunchKernelGGL(k_winner, dim3(NB), dim3(256), 0, stream, out, out);
}